// Round 8
// baseline (443.223 us; speedup 1.0000x reference)
//
#include <hip/hip_runtime.h>
#include <stdint.h>

typedef unsigned short u16;
typedef _Float16 half8 __attribute__((ext_vector_type(8)));
typedef float floatx4 __attribute__((ext_vector_type(4)));
typedef u16 u16x4 __attribute__((ext_vector_type(4)));

#define B_ 2
#define S_ 2048
#define HID_ 2048
#define H_ 16
#define HKV_ 4
#define D_ 128
#define NB_ 32
#define SCALE_ 0.08838834764831845f
// p = exp(s*SCALE - 4) == exp2(fma(s, SC_L2, -SMAX_L2))
#define SC_L2 0.12753102331884178f
#define SMAX_L2 5.770780163555852f

__device__ __forceinline__ u16 f2h_bits(float f) {
  _Float16 h = (_Float16)f;
  return __builtin_bit_cast(u16, h);
}

// ---- split hidden_states into [s0 | s1] f16 blocks (2-way split), row-major lda=4096 ----
__global__ __launch_bounds__(256) void k_split_hs(const float* __restrict__ hs, u16* __restrict__ A2) {
  int idx = blockIdx.x * 256 + threadIdx.x;
  int f0 = idx * 4;
  float4 v = *reinterpret_cast<const float4*>(hs + f0);
  float vv[4] = {v.x, v.y, v.z, v.w};
  u16x4 h0, h1;
#pragma unroll
  for (int e = 0; e < 4; ++e) {
    _Float16 a = (_Float16)vv[e];
    float r = vv[e] - (float)a;
    _Float16 b = (_Float16)r;
    h0[e] = __builtin_bit_cast(u16, a);
    h1[e] = __builtin_bit_cast(u16, b);
  }
  int row = f0 >> 11;
  int col = f0 & 2047;
  *reinterpret_cast<u16x4*>(A2 + (size_t)row * 4096 + col) = h0;
  *reinterpret_cast<u16x4*>(A2 + (size_t)row * 4096 + 2048 + col) = h1;
}

// ---- transpose W (Kdim x N) -> dst rows n: [split0 K | split1 K ...], f16 ----
__global__ __launch_bounds__(256) void k_transpose_split(const float* __restrict__ src, u16* __restrict__ dst,
                                                         int Kdim, int N, int ldd, int nsplit) {
  __shared__ float tile[64][65];
  int k0 = blockIdx.x * 64, n0 = blockIdx.y * 64;
#pragma unroll
  for (int p = 0; p < 16; ++p) {
    int e = threadIdx.x + p * 256;
    int r = e >> 6, c = e & 63;
    tile[r][c] = src[(size_t)(k0 + r) * N + n0 + c];
  }
  __syncthreads();
#pragma unroll
  for (int p = 0; p < 16; ++p) {
    int e = threadIdx.x + p * 256;
    int k = e & 63, n = e >> 6;
    float v = tile[k][n];
    for (int s = 0; s < nsplit; ++s) {
      _Float16 hh = (_Float16)v;
      dst[(size_t)(n0 + n) * ldd + s * Kdim + k0 + k] = __builtin_bit_cast(u16, hh);
      v -= (float)hh;
    }
  }
}

// ---- out += P1 (split-K reduction, float4) ----
__global__ __launch_bounds__(256) void k_add(float4* __restrict__ out, const float4* __restrict__ p1) {
  size_t i = (size_t)blockIdx.x * 256 + threadIdx.x;
  float4 a = out[i], b = p1[i];
  out[i] = (float4){a.x + b.x, a.y + b.y, a.z + b.z, a.w + b.w};
}

// ============ 256x256 GEMM, BK=64, 2x64KB LDS double-buffer (128KB static) ============
// Per buffer (u16 units): A-lo[0,8192) A-hi[8192,16384) B-lo[16384,24576) B-hi[24576,32768);
// buf1 at +32768. Half = 128 rows x 64 f16 (128B rows), 16B-granule XOR swizzle
// phys_slot = log_slot ^ (row&7); staged linearly via global_load_lds with inverse-swizzled
// GLOBAL source (rule 21). 8 waves = 2(M) x 4(N); per-wave output 128x64 interleaved.
// Schedule: ONE region per K-tile. Region t: (a) stage tile t+1 into buf^1 FIRST (8 gloads,
// issued early so they fly under the MFMAs ~2500cy >> 900cy HBM latency); (b) 24 ds_reads +
// 64 MFMA from buf; (c) WAITVM(0) (drains own stages) + s_barrier. 1 barrier/K-tile vs the
// old ring's 8. Races: stages write buf^1 while reads hit buf (disjoint); buf^1's previous
// readers finished before the prior barrier; all waves' stages land before next region's
// reads (own drain + barrier). Registers cap residency at 1 block/CU anyway, so 128KB LDS
// costs no occupancy.
// Epilogue: f32 store, or f16 store to a u16 buffer (correction partials).

#define FENCE() __builtin_amdgcn_sched_barrier(0)
#define BAR() do { FENCE(); __builtin_amdgcn_s_barrier(); FENCE(); } while (0)
#define WAITVM(N) do { FENCE(); asm volatile("s_waitcnt vmcnt(" #N ")" ::: "memory"); FENCE(); } while (0)

__device__ __forceinline__ int kmap(int map, int t) {
  // K-tile t (64 elems) -> source column base via 4-bit nibbles of map (2048-elem segments)
  return ((map >> ((t >> 5) * 4)) & 15) * 2048 + (t & 31) * 64;
}

__device__ __forceinline__ void stage_half(const u16* __restrict__ src, int sr0, int lda, int kb,
                                           u16* dst, int w, int lane) {
#pragma unroll
  for (int rr = 0; rr < 2; ++rr) {
    int chunk = rr * 8 + w;                  // 0..15, wave-uniform
    int row = chunk * 8 + (lane >> 3);       // 0..127
    int slot = (lane & 7) ^ (lane >> 3);     // inverse swizzle (row&7 == lane>>3)
    const u16* gp = src + (size_t)(sr0 + row) * lda + kb + slot * 8;
    __builtin_amdgcn_global_load_lds((const __attribute__((address_space(1))) unsigned int*)gp,
                                     (__attribute__((address_space(3))) unsigned int*)(dst + chunk * 512),
                                     16, 0, 0);
  }
}

#define RD_A(RB, mh) do { \
  _Pragma("unroll") \
  for (int m_ = 0; m_ < 4; ++m_) { \
    aF[m_][0] = *reinterpret_cast<const half8*>(&sm[(RB) + (mh)*8192 + (wm*64 + m_*16 + l15)*64 + ((quad ^ l7) * 8)]); \
    aF[m_][1] = *reinterpret_cast<const half8*>(&sm[(RB) + (mh)*8192 + (wm*64 + m_*16 + l15)*64 + (((4 + quad) ^ l7) * 8)]); \
  } } while (0)

#define RD_B(RB, nh, BF) do { \
  _Pragma("unroll") \
  for (int n_ = 0; n_ < 2; ++n_) { \
    BF[n_][0] = *reinterpret_cast<const half8*>(&sm[(RB) + 16384 + (nh)*8192 + (wn*32 + n_*16 + l15)*64 + ((quad ^ l7) * 8)]); \
    BF[n_][1] = *reinterpret_cast<const half8*>(&sm[(RB) + 16384 + (nh)*8192 + (wn*32 + n_*16 + l15)*64 + (((4 + quad) ^ l7) * 8)]); \
  } } while (0)

#define MM(mh, nh, BF) do { \
  __builtin_amdgcn_s_setprio(1); \
  _Pragma("unroll") \
  for (int m_ = 0; m_ < 4; ++m_) \
  _Pragma("unroll") \
  for (int n_ = 0; n_ < 2; ++n_) { \
    acc[(mh)*4 + m_][(nh)*2 + n_] = __builtin_amdgcn_mfma_f32_16x16x32_f16(aF[m_][0], BF[n_][0], acc[(mh)*4 + m_][(nh)*2 + n_], 0, 0, 0); \
    acc[(mh)*4 + m_][(nh)*2 + n_] = __builtin_amdgcn_mfma_f32_16x16x32_f16(aF[m_][1], BF[n_][1], acc[(mh)*4 + m_][(nh)*2 + n_], 0, 0, 0); \
  } \
  __builtin_amdgcn_s_setprio(0); } while (0)

// One K-tile region: stage tile tn into SB, compute tile tcur from RB, drain, barrier.
#define ITER(tcur, RB, SB) do { \
  int tn = (tcur) + 1; if (tn >= NT) tn = 0; \
  int kan = kmap(amap, tn) + koffA, kbn = kmap(bmap, tn) + koffB; \
  stage_half(A,  row0,       lda, kan, sm + (SB) + 0,     w, lane); \
  stage_half(A,  row0 + 128, lda, kan, sm + (SB) + 8192,  w, lane); \
  stage_half(BT, col0,       ldb, kbn, sm + (SB) + 16384, w, lane); \
  stage_half(BT, col0 + 128, ldb, kbn, sm + (SB) + 24576, w, lane); \
  RD_A(RB, 0); RD_B(RB, 0, bF0); MM(0, 0, bF0); \
  RD_B(RB, 1, bF1); MM(0, 1, bF1); \
  RD_A(RB, 1); MM(1, 1, bF1); MM(1, 0, bF0); \
  WAITVM(0); BAR(); \
} while (0)

__device__ __forceinline__ void gemm256(const u16* __restrict__ A, const u16* __restrict__ BT,
                                        float* __restrict__ C, u16* __restrict__ Ch, u16* sm,
                                        int row0, int col0, int NT,
                                        int lda, int ldb, int ldc, int ldch,
                                        int amap, int bmap, int koffA, int koffB) {
  const int tid = (int)threadIdx.x;
  const int lane = tid & 63;
  const int w = tid >> 6;
  const int wm = w >> 2, wn = w & 3;
  const int quad = lane >> 4, l15 = lane & 15, l7 = lane & 7;

  floatx4 acc[8][4];
#pragma unroll
  for (int i = 0; i < 8; ++i)
#pragma unroll
    for (int j = 0; j < 4; ++j) acc[i][j] = (floatx4){0.f, 0.f, 0.f, 0.f};

  half8 aF[4][2], bF0[2][2], bF1[2][2];

  // prologue: stage tile 0 into buf0
  {
    int ka = kmap(amap, 0) + koffA, kb = kmap(bmap, 0) + koffB;
    stage_half(A,  row0,       lda, ka, sm + 0,     w, lane);
    stage_half(A,  row0 + 128, lda, ka, sm + 8192,  w, lane);
    stage_half(BT, col0,       ldb, kb, sm + 16384, w, lane);
    stage_half(BT, col0 + 128, ldb, kb, sm + 24576, w, lane);
  }
  WAITVM(0);
  BAR();

  // NT is a multiple of 2 for all call sites (16/32/64)
  for (int t = 0; t < NT; t += 2) {
    ITER(t,     0,     32768);   // read buf0, stage t+1 -> buf1
    ITER(t + 1, 32768, 0);       // read buf1, stage t+2 -> buf0
  }

  // epilogue: f32 store, or f16 store (correction partial)
#pragma unroll
  for (int i = 0; i < 8; ++i) {
    int mh = i >> 2, m = i & 3;
#pragma unroll
    for (int j = 0; j < 4; ++j) {
      int nh = j >> 1, n = j & 1;
#pragma unroll
      for (int r = 0; r < 4; ++r) {
        int rr = row0 + mh * 128 + wm * 64 + m * 16 + quad * 4 + r;
        int cc = col0 + nh * 128 + wn * 32 + n * 16 + l15;
        if (Ch)
          Ch[(size_t)rr * ldch + cc] = f2h_bits(acc[i][j][r]);
        else
          C[(size_t)rr * ldc + cc] = acc[i][j][r];
      }
    }
  }
}

// ---- fused QKV projection, balanced 352-block grid, no atomics ----
// ids 0..159:  correction GEMM  (a1*b0 | a0*b1 concat along K=4096), NT=64, f16 -> corr scratch
// ids 160..319: main QK product (a0*b0), NT=32, f32 -> qkv cols [0,2560)
// ids 320..351: V projection,            NT=32, f32 -> qkv cols [2560,3072)
__global__ __launch_bounds__(512) void k_gemm_qkv(const u16* __restrict__ A2, const u16* __restrict__ B2T,
                                                  const u16* __restrict__ WvT, float* __restrict__ qkv,
                                                  u16* __restrict__ corr) {
  __shared__ u16 sm[65536];   // 128KB double buffer
  int id = blockIdx.x;
  if (id < 160) {
    int row0 = (id / 10) * 256, col0 = (id % 10) * 256;
    gemm256(A2, B2T, nullptr, corr, sm, row0, col0, 64, 4096, 4096, 0, 2560, 0x01, 0x10, 0, 0);
  } else if (id < 320) {
    int t = id - 160;
    int row0 = (t / 10) * 256, col0 = (t % 10) * 256;
    gemm256(A2, B2T, qkv, nullptr, sm, row0, col0, 32, 4096, 4096, 3072, 0, 0, 0, 0, 0);
  } else {
    int t = id - 320;
    int row0 = (t >> 1) * 256, col0 = (t & 1) * 256;
    gemm256(A2, WvT, qkv + 2560, nullptr, sm, row0, col0, 32, 4096, 2048, 3072, 0, 0, 0, 0, 0);
  }
}

// ---- out = attn @ Wo, split-K=2: 256 uniform blocks (NT=16), p=0 -> out, p=1 -> P1; then k_add ----
__global__ __launch_bounds__(512) void k_gemm_wo(const u16* __restrict__ attn, const u16* __restrict__ WoT,
                                                 float* __restrict__ out, float* __restrict__ P1) {
  __shared__ u16 sm[65536];   // 128KB double buffer
  int id = blockIdx.x;
  int p = id >> 7, rem = id & 127;
  int row0 = (rem >> 3) * 256, col0 = (rem & 7) * 256;
  float* Cp = p ? P1 : out;
  gemm256(attn, WoT, Cp, nullptr, sm, row0, col0, 16, 2048, 2048, 2048, 0, 0, 0,
          p * 1024, p * 1024);
}

// ---- RoPE (+f16 correction add) + write q/k f16 + fp32 block means ----
__global__ __launch_bounds__(256) void k_rope_mean(const float* __restrict__ qkv, const u16* __restrict__ corr,
                                                   const float* __restrict__ cosb, const float* __restrict__ sinb,
                                                   u16* __restrict__ qbf, u16* __restrict__ kbf,
                                                   float* __restrict__ qblk, float* __restrict__ kblk) {
  int cc = blockIdx.x, i = blockIdx.y, b = blockIdx.z;
  int c = cc * 256 + threadIdx.x;          // 0..2559 (q cols 0..2047, k cols 2048..2559)
  bool isq = c < 2048;
  int hh = isq ? (c >> 7) : ((c - 2048) >> 7);
  int d = isq ? (c & 127) : ((c - 2048) & 127);
  int pairc = (d < 64) ? c + 64 : c - 64;
  float sgn = (d < 64) ? -1.0f : 1.0f;
  int row0 = b * S_ + i * 64;
  float sum = 0.0f;
  for (int s = 0; s < 64; ++s) {
    int row = row0 + s;
    float x1 = qkv[(size_t)row * 3072 + c]
             + (float)__builtin_bit_cast(_Float16, corr[(size_t)row * 2560 + c]);
    float x2 = qkv[(size_t)row * 3072 + pairc]
             + (float)__builtin_bit_cast(_Float16, corr[(size_t)row * 2560 + pairc]);
    float cv = cosb[(size_t)row * 128 + d];
    float sv = sinb[(size_t)row * 128 + d];
    float val = x1 * cv + sgn * x2 * sv;
    sum += val;
    if (isq)
      qbf[((size_t)(b * H_ + hh) * S_ + i * 64 + s) * 128 + d] = f2h_bits(val);
    else
      kbf[((size_t)(b * HKV_ + hh) * S_ + i * 64 + s) * 128 + d] = f2h_bits(val);
  }
  if (isq)
    qblk[((size_t)(b * H_ + hh) * NB_ + i) * 128 + d] = sum * 0.015625f;
  else
    kblk[((size_t)(b * HKV_ + hh) * NB_ + i) * 128 + d] = sum * 0.015625f;
}

// ---- V -> f16 transposed layout (B,HKV,D,S) ----
__global__ __launch_bounds__(256) void k_vlayout(const float* __restrict__ qkv, u16* __restrict__ vT) {
  int i = blockIdx.x, hk = blockIdx.y, b = blockIdx.z;
  __shared__ u16 tile[64 * 130];
#pragma unroll
  for (int p = 0; p < 32; ++p) {
    int e = threadIdx.x + p * 256;
    int s = e >> 7, d = e & 127;
    float v = qkv[(size_t)(b * S_ + i * 64 + s) * 3072 + 2560 + hk * 128 + d];
    tile[s * 130 + d] = f2h_bits(v);
  }
  __syncthreads();
#pragma unroll
  for (int p = 0; p < 32; ++p) {
    int e = threadIdx.x + p * 256;
    int d2 = e >> 6, s2 = e & 63;
    vT[((size_t)(b * HKV_ + hk) * 128 + d2) * S_ + i * 64 + s2] = tile[s2 * 130 + d2];
  }
}

// ---- gate mask: sigmoid(logit)>=0.5 <=> dot>=0; | eye; & tril ----
__global__ __launch_bounds__(256) void k_gate(const float* __restrict__ qblk, const float* __restrict__ kblk,
                                              int* __restrict__ mask) {
  int h = blockIdx.x, b = blockIdx.y;
  int hk = h >> 2;
  __shared__ float qs[32 * 128];
  __shared__ float ks[32 * 128];
  size_t qb0 = (size_t)(b * H_ + h) * NB_ * 128;
  size_t kb0 = (size_t)(b * HKV_ + hk) * NB_ * 128;
#pragma unroll
  for (int p = 0; p < 16; ++p) {
    int e = threadIdx.x + p * 256;
    qs[e] = qblk[qb0 + e];
    ks[e] = kblk[kb0 + e];
  }
  __syncthreads();
#pragma unroll
  for (int p = 0; p < 4; ++p) {
    int l = threadIdx.x + p * 256;
    int i = l >> 5, j = l & 31;
    int m;
    if (j > i) m = 0;
    else if (j == i) m = 1;
    else {
      float dot = 0.0f;
      for (int d = 0; d < 128; ++d) dot += qs[i * 128 + d] * ks[j * 128 + d];
      m = (dot >= 0.0f) ? 1 : 0;
    }
    mask[((size_t)(b * H_ + h) * NB_ + i) * NB_ + j] = m;
  }
}

// ---- block-sparse flash attention, static-max softmax (round-5-proven LDS-staged form) ----
__global__ __launch_bounds__(256) void k_flash(const u16* __restrict__ qbf, const u16* __restrict__ kbf,
                                               const u16* __restrict__ vT, const int* __restrict__ mask,
                                               u16* __restrict__ attn) {
  const int id = blockIdx.x;
  const int i = id >> 5;
  const int hb = id & 31;
  const int h = hb & 15, b = hb >> 4;
  const int hk = h >> 2;
  const int tid = threadIdx.x;
  const int lane = tid & 63;
  const int w = tid >> 6;
  const int quad = lane >> 4;
  const int l15 = lane & 15;

  __shared__ u16 Ks[64 * 128];    // [tok][d], 16B-granule XOR swizzle: u_phys = u ^ (tok&15)
  __shared__ u16 Vs[128 * 64];    // [d][tok], u_phys = u ^ (dd&7)
  __shared__ u16 Ps[4 * 16 * 64]; // per-wave [m][k]

  half8 qF[4];
  const u16* qbase = qbf + ((size_t)(b * H_ + h) * S_ + i * 64 + w * 16 + l15) * 128;
#pragma unroll
  for (int kk = 0; kk < 4; ++kk)
    qF[kk] = *reinterpret_cast<const half8*>(qbase + kk * 32 + quad * 8);

  floatx4 o[8];
#pragma unroll
  for (int t = 0; t < 8; ++t) o[t] = (floatx4){0.f, 0.f, 0.f, 0.f};
  float ls[4] = {0.f, 0.f, 0.f, 0.f};

  const u16* kb = kbf + (size_t)(b * HKV_ + hk) * S_ * 128;
  const u16* vb = vT + (size_t)(b * HKV_ + hk) * 128 * S_;
  const int* mrp = mask + ((size_t)(b * H_ + h) * NB_ + i) * NB_;

  for (int j = 0; j <= i; ++j) {
    if (!mrp[j]) continue;
#pragma unroll
    for (int t = 0; t < 4; ++t) {
      int g2 = t * 4 + w;
      int stok = g2 * 4 + (lane >> 4);
      int ul = (lane & 15) ^ (stok & 15);
      const u16* srcK = kb + (size_t)(j * 64 + stok) * 128 + ul * 8;
      __builtin_amdgcn_global_load_lds((const __attribute__((address_space(1))) unsigned int*)srcK,
                                       (__attribute__((address_space(3))) unsigned int*)(Ks + g2 * 512),
                                       16, 0, 0);
      int sdd = g2 * 8 + (lane >> 3);
      int ulv = (lane & 7) ^ (sdd & 7);
      const u16* srcV = vb + (size_t)sdd * S_ + j * 64 + ulv * 8;
      __builtin_amdgcn_global_load_lds((const __attribute__((address_space(1))) unsigned int*)srcV,
                                       (__attribute__((address_space(3))) unsigned int*)(Vs + g2 * 512),
                                       16, 0, 0);
    }
    __syncthreads();

#pragma unroll
    for (int ct = 0; ct < 4; ++ct) {
      floatx4 cacc = (floatx4){0.f, 0.f, 0.f, 0.f};
#pragma unroll
      for (int kk = 0; kk < 4; ++kk) {
        int phys = (kk * 4 + quad) ^ l15;
        half8 bF = *reinterpret_cast<const half8*>(&Ks[(ct * 16 + l15) * 128 + phys * 8]);
        cacc = __builtin_amdgcn_mfma_f32_16x16x32_f16(qF[kk], bF, cacc, 0, 0, 0);
      }
#pragma unroll
      for (int r = 0; r < 4; ++r) {
        float s = cacc[r];
        if (j == i && (ct * 16 + l15) > (w * 16 + quad * 4 + r)) s = -1e30f;
        float p = __builtin_exp2f(fmaf(s, SC_L2, -SMAX_L2));
        _Float16 ph = (_Float16)p;           // quantize ONCE; numerator and
        ls[r] += (float)ph;                  // denominator see the same value
        Ps[w * 1024 + (quad * 4 + r) * 64 + ct * 16 + l15] = __builtin_bit_cast(u16, ph);
      }
    }
#pragma unroll
    for (int kk2 = 0; kk2 < 2; ++kk2) {
      half8 aP = *reinterpret_cast<const half8*>(&Ps[w * 1024 + l15 * 64 + kk2 * 32 + quad * 8]);
#pragma unroll
      for (int ct2 = 0; ct2 < 8; ++ct2) {
        int phys = (kk2 * 4 + quad) ^ (l15 & 7);
        half8 bV = *reinterpret_cast<const half8*>(&Vs[(ct2 * 16 + l15) * 64 + phys * 8]);
        o[ct2] = __builtin_amdgcn_mfma_f32_16x16x32_f16(aP, bV, o[ct2], 0, 0, 0);
      }
    }
    __syncthreads();
  }

#pragma unroll
  for (int xm = 1; xm < 16; xm <<= 1)
#pragma unroll
    for (int r = 0; r < 4; ++r) ls[r] += __shfl_xor(ls[r], xm, 64);
  float invl[4];
#pragma unroll
  for (int r = 0; r < 4; ++r) invl[r] = 1.0f / ls[r];
#pragma unroll
  for (int ct2 = 0; ct2 < 8; ++ct2)
#pragma unroll
    for (int r = 0; r < 4; ++r) {
      size_t row = (size_t)(b * S_ + i * 64 + w * 16 + quad * 4 + r);
      attn[row * 2048 + h * 128 + ct2 * 16 + l15] = f2h_bits(o[ct2][r] * invl[r]);
    }
}

extern "C" void kernel_launch(void* const* d_in, const int* in_sizes, int n_in,
                              void* d_out, int out_size, void* d_ws, size_t ws_size,
                              hipStream_t stream) {
  const float* hs = (const float*)d_in[0];
  const float* cosb = (const float*)d_in[1];
  const float* sinb = (const float*)d_in[2];
  const float* Wq = (const float*)d_in[3];
  const float* Wk = (const float*)d_in[4];
  const float* Wv = (const float*)d_in[5];
  const float* Wo = (const float*)d_in[6];
  float* out = (float*)d_out;
  char* ws = (char*)d_ws;

  // phase-1 buffers
  u16* A2 = (u16*)(ws + 0);               // 4096x4096 f16 (hs splits [s0|s1])        [0, 33.5M)
  u16* B2T = (u16*)(ws + 33554432);       // 2560x4096 f16 ([WqT;WkT] splits [t0|t1]) [33.5M, 54.5M)
  u16* WvT = (u16*)(ws + 54525952);       // 512x2048 f16                             [54.5M, 56.6M)
  float* qkv = (float*)(ws + 56623104);   // 4096x3072 f32                            [56.6M, 107M)
  u16* corr = (u16*)out;                  // 4096x2560 f16 correction partial -- d_out is dead
                                          // until k_gemm_wo overwrites it at the very end
  // phase-2 aliases (dead GEMM inputs reused)
  u16* attn = (u16*)(ws + 0);             // 4096x2048 f16  (in dead A2)
  u16* qbf = (u16*)(ws + 16777216);       // (in dead A2)
  u16* kbf = (u16*)(ws + 33554432);       // (in dead B2T)
  u16* vTbf = (u16*)(ws + 37748736);
  float* qblk = (float*)(ws + 41943040);
  float* kblk = (float*)(ws + 42467328);
  int* mask = (int*)(ws + 42598400);
  u16* WoT = (u16*)(ws + 43122688);       // 2048x2048 f16  (in dead B2T; written after QK GEMM)
  float* P1 = (float*)(ws + 56623104);    // 4096x2048 f32 split-K partial (in dead qkv region)

  (void)in_sizes; (void)n_in; (void)out_size; (void)ws_size;

  // prep
  k_split_hs<<<8192, 256, 0, stream>>>(hs, A2);
  k_transpose_split<<<dim3(32, 32), 256, 0, stream>>>(Wq, B2T, 2048, 2048, 4096, 2);
  k_transpose_split<<<dim3(32, 8), 256, 0, stream>>>(Wk, B2T + (size_t)2048 * 4096, 2048, 512, 4096, 2);
  k_transpose_split<<<dim3(32, 8), 256, 0, stream>>>(Wv, WvT, 2048, 512, 2048, 1);

  // QKV: balanced 352 blocks (corr NT=64 first; main + V NT=32 backfill); no atomics
  k_gemm_qkv<<<352, 512, 0, stream>>>(A2, B2T, WvT, qkv, corr);

  // Wo transpose into dead B2T space (after QK GEMM consumed B2T)
  k_transpose_split<<<dim3(32, 32), 256, 0, stream>>>(Wo, WoT, 2048, 2048, 2048, 1);

  // RoPE (+corr add) + f16 q/k + fp32 block means; V layout
  k_rope_mean<<<dim3(10, 32, 2), 256, 0, stream>>>(qkv, corr, cosb, sinb, qbf, kbf, qblk, kblk);
  k_vlayout<<<dim3(32, 4, 2), 256, 0, stream>>>(qkv, vTbf);

  // gate mask
  k_gate<<<dim3(16, 2), 256, 0, stream>>>(qblk, kblk, mask);

  // block-sparse flash attention (round-5-proven LDS-staged form)
  k_flash<<<1024, 256, 0, stream>>>(qbf, kbf, vTbf, mask, attn);

  // out = attn @ Wo: split-K=2, 256 uniform blocks (full chip), then reduce
  k_gemm_wo<<<256, 512, 0, stream>>>(attn, WoT, out, P1);
  k_add<<<8192, 256, 0, stream>>>((float4*)out, (const float4*)P1);
}

// Round 9
// 405.001 us; speedup vs baseline: 1.0944x; 1.0944x over previous
//
#include <hip/hip_runtime.h>
#include <stdint.h>

typedef unsigned short u16;
typedef _Float16 half8 __attribute__((ext_vector_type(8)));
typedef float floatx4 __attribute__((ext_vector_type(4)));
typedef u16 u16x4 __attribute__((ext_vector_type(4)));

#define B_ 2
#define S_ 2048
#define HID_ 2048
#define H_ 16
#define HKV_ 4
#define D_ 128
#define NB_ 32
#define SCALE_ 0.08838834764831845f
// p = exp(s*SCALE - 4) == exp2(fma(s, SC_L2, -SMAX_L2))
#define SC_L2 0.12753102331884178f
#define SMAX_L2 5.770780163555852f

__device__ __forceinline__ u16 f2h_bits(float f) {
  _Float16 h = (_Float16)f;
  return __builtin_bit_cast(u16, h);
}

// ---- transpose body: W (Kdim x N) tile -> dst rows n: [split0 K | split1 K ...], f16 ----
__device__ __forceinline__ void transpose_body(const float* __restrict__ src, u16* __restrict__ dst,
                                               int Kdim, int N, int ldd, int nsplit,
                                               int k0, int n0, float (*tile)[65]) {
#pragma unroll
  for (int p = 0; p < 16; ++p) {
    int e = threadIdx.x + p * 256;
    int r = e >> 6, c = e & 63;
    tile[r][c] = src[(size_t)(k0 + r) * N + n0 + c];
  }
  __syncthreads();
#pragma unroll
  for (int p = 0; p < 16; ++p) {
    int e = threadIdx.x + p * 256;
    int k = e & 63, n = e >> 6;
    float v = tile[k][n];
    for (int s = 0; s < nsplit; ++s) {
      _Float16 hh = (_Float16)v;
      dst[(size_t)(n0 + n) * ldd + s * Kdim + k0 + k] = __builtin_bit_cast(u16, hh);
      v -= (float)hh;
    }
  }
}

// ---- fused prep: split_hs (8192 blocks) + Wq (1024) + Wk (256) + Wv (256) transposes ----
__global__ __launch_bounds__(256) void k_prep(const float* __restrict__ hs, u16* __restrict__ A2,
                                              const float* __restrict__ Wq, const float* __restrict__ Wk,
                                              const float* __restrict__ Wv,
                                              u16* __restrict__ B2T, u16* __restrict__ WvT) {
  __shared__ float tile[64][65];
  int id = blockIdx.x;
  if (id < 8192) {
    int idx = id * 256 + threadIdx.x;
    int f0 = idx * 4;
    float4 v = *reinterpret_cast<const float4*>(hs + f0);
    float vv[4] = {v.x, v.y, v.z, v.w};
    u16x4 h0, h1;
#pragma unroll
    for (int e = 0; e < 4; ++e) {
      _Float16 a = (_Float16)vv[e];
      float r = vv[e] - (float)a;
      _Float16 b = (_Float16)r;
      h0[e] = __builtin_bit_cast(u16, a);
      h1[e] = __builtin_bit_cast(u16, b);
    }
    int row = f0 >> 11;
    int col = f0 & 2047;
    *reinterpret_cast<u16x4*>(A2 + (size_t)row * 4096 + col) = h0;
    *reinterpret_cast<u16x4*>(A2 + (size_t)row * 4096 + 2048 + col) = h1;
  } else if (id < 9216) {
    int t = id - 8192;
    transpose_body(Wq, B2T, 2048, 2048, 4096, 2, (t & 31) * 64, (t >> 5) * 64, tile);
  } else if (id < 9472) {
    int t = id - 9216;
    transpose_body(Wk, B2T + (size_t)2048 * 4096, 2048, 512, 4096, 2, (t & 31) * 64, (t >> 5) * 64, tile);
  } else {
    int t = id - 9472;
    transpose_body(Wv, WvT, 2048, 512, 2048, 1, (t & 31) * 64, (t >> 5) * 64, tile);
  }
}

// ---- standalone transpose (Wo, must run after QK GEMM) ----
__global__ __launch_bounds__(256) void k_transpose_split(const float* __restrict__ src, u16* __restrict__ dst,
                                                         int Kdim, int N, int ldd, int nsplit) {
  __shared__ float tile[64][65];
  transpose_body(src, dst, Kdim, N, ldd, nsplit, blockIdx.x * 64, blockIdx.y * 64, tile);
}

// ---- out += P1 (split-K reduction, float4) ----
__global__ __launch_bounds__(256) void k_add(float4* __restrict__ out, const float4* __restrict__ p1) {
  size_t i = (size_t)blockIdx.x * 256 + threadIdx.x;
  float4 a = out[i], b = p1[i];
  out[i] = (float4){a.x + b.x, a.y + b.y, a.z + b.z, a.w + b.w};
}

// ============ 256x256 GEMM, BK=64, 4-half LDS ring, counted vmcnt (64KB static LDS) ============
// (round-7-proven form; round-8's drain-0 double-buffer regressed — T4 confirmed on this kernel)
// Halves (u16 units): A-lo [0,8192) A-hi [8192,16384) B-lo [16384,24576) B-hi [24576,32768).
// Half = 128 rows x 64 f16, 16B-granule XOR swizzle phys_slot = log_slot ^ (row&7); staged
// linearly via global_load_lds with inverse-swizzled GLOBAL source (rule 21).
// Ledger (2 loads per stage_half per thread), invariant entering ph1: 4.
//   ph1: RD AL,BL            ; wait vmcnt(2)  [drains BH(t);  AH(t) in flight]
//   ph2: RD BH ; stage AL',BL'; wait vmcnt(4) [drains AH(t);  AL'BL' in flight]
//   ph3: RD AH ; stage BH'    ; (no wait)
//   ph4: stage AH'            ; wait vmcnt(4) [drains AL'BL'; BH'AH' in flight]

#define FENCE() __builtin_amdgcn_sched_barrier(0)
#define BAR() do { FENCE(); __builtin_amdgcn_s_barrier(); FENCE(); } while (0)
#define WAITVM(N) do { FENCE(); asm volatile("s_waitcnt vmcnt(" #N ")" ::: "memory"); FENCE(); } while (0)

__device__ __forceinline__ int kmap(int map, int t) {
  return ((map >> ((t >> 5) * 4)) & 15) * 2048 + (t & 31) * 64;
}

__device__ __forceinline__ void stage_half(const u16* __restrict__ src, int sr0, int lda, int kb,
                                           u16* dst, int w, int lane) {
#pragma unroll
  for (int rr = 0; rr < 2; ++rr) {
    int chunk = rr * 8 + w;                  // 0..15, wave-uniform
    int row = chunk * 8 + (lane >> 3);       // 0..127
    int slot = (lane & 7) ^ (lane >> 3);     // inverse swizzle (row&7 == lane>>3)
    const u16* gp = src + (size_t)(sr0 + row) * lda + kb + slot * 8;
    __builtin_amdgcn_global_load_lds((const __attribute__((address_space(1))) unsigned int*)gp,
                                     (__attribute__((address_space(3))) unsigned int*)(dst + chunk * 512),
                                     16, 0, 0);
  }
}

#define RD_A(mh) do { \
  _Pragma("unroll") \
  for (int m_ = 0; m_ < 4; ++m_) { \
    aF[m_][0] = *reinterpret_cast<const half8*>(&sm[(mh)*8192 + (wm*64 + m_*16 + l15)*64 + ((quad ^ l7) * 8)]); \
    aF[m_][1] = *reinterpret_cast<const half8*>(&sm[(mh)*8192 + (wm*64 + m_*16 + l15)*64 + (((4 + quad) ^ l7) * 8)]); \
  } } while (0)

#define RD_B(nh, BF) do { \
  _Pragma("unroll") \
  for (int n_ = 0; n_ < 2; ++n_) { \
    BF[n_][0] = *reinterpret_cast<const half8*>(&sm[16384 + (nh)*8192 + (wn*32 + n_*16 + l15)*64 + ((quad ^ l7) * 8)]); \
    BF[n_][1] = *reinterpret_cast<const half8*>(&sm[16384 + (nh)*8192 + (wn*32 + n_*16 + l15)*64 + (((4 + quad) ^ l7) * 8)]); \
  } } while (0)

#define MM(mh, nh, BF) do { \
  __builtin_amdgcn_s_setprio(1); \
  _Pragma("unroll") \
  for (int m_ = 0; m_ < 4; ++m_) \
  _Pragma("unroll") \
  for (int n_ = 0; n_ < 2; ++n_) { \
    acc[(mh)*4 + m_][(nh)*2 + n_] = __builtin_amdgcn_mfma_f32_16x16x32_f16(aF[m_][0], BF[n_][0], acc[(mh)*4 + m_][(nh)*2 + n_], 0, 0, 0); \
    acc[(mh)*4 + m_][(nh)*2 + n_] = __builtin_amdgcn_mfma_f32_16x16x32_f16(aF[m_][1], BF[n_][1], acc[(mh)*4 + m_][(nh)*2 + n_], 0, 0, 0); \
  } \
  __builtin_amdgcn_s_setprio(0); } while (0)

__device__ __forceinline__ void gemm256(const u16* __restrict__ A, const u16* __restrict__ BT,
                                        float* __restrict__ C, u16* __restrict__ Ch, u16* sm,
                                        int row0, int col0, int NT,
                                        int lda, int ldb, int ldc, int ldch,
                                        int amap, int bmap, int koffA, int koffB) {
  const int tid = (int)threadIdx.x;
  const int lane = tid & 63;
  const int w = tid >> 6;
  const int wm = w >> 2, wn = w & 3;
  const int quad = lane >> 4, l15 = lane & 15, l7 = lane & 7;

  floatx4 acc[8][4];
#pragma unroll
  for (int i = 0; i < 8; ++i)
#pragma unroll
    for (int j = 0; j < 4; ++j) acc[i][j] = (floatx4){0.f, 0.f, 0.f, 0.f};

  half8 aF[4][2], bF0[2][2], bF1[2][2];

  // prologue: stage tile 0 (AL,BL oldest so vmcnt(4) drains them first)
  {
    int ka = kmap(amap, 0) + koffA, kb = kmap(bmap, 0) + koffB;
    stage_half(A,  row0,       lda, ka, sm + 0,     w, lane);  // AL
    stage_half(BT, col0,       ldb, kb, sm + 16384, w, lane);  // BL
    stage_half(BT, col0 + 128, ldb, kb, sm + 24576, w, lane);  // BH
    stage_half(A,  row0 + 128, lda, ka, sm + 8192,  w, lane);  // AH
  }
  WAITVM(4);   // own AL,BL landed; BH,AH in flight
  BAR();       // all waves' AL,BL landed before any ds_read

  for (int t = 0; t < NT; ++t) {
    int tn = t + 1; if (tn >= NT) tn = 0;    // clamp keeps vmcnt counts uniform
    int kan = kmap(amap, tn) + koffA, kbn = kmap(bmap, tn) + koffB;

    // ph1: quad(0,0) reads AL,BL
    RD_A(0); RD_B(0, bF0);
    WAITVM(2);                                            // BH(t) confirmed (AH in flight)
    BAR(); MM(0, 0, bF0); BAR();
    // ph2: quad(0,1) reads BH; AL,BL free -> restage for t+1
    RD_B(1, bF1);
    stage_half(A,  row0, lda, kan, sm + 0,     w, lane);  // AL <- t+1
    stage_half(BT, col0, ldb, kbn, sm + 16384, w, lane);  // BL <- t+1
    WAITVM(4);                                            // AH(t) confirmed (AL',BL' in flight)
    BAR(); MM(0, 1, bF1); BAR();
    // ph3: quad(1,1) reads AH; BH free -> restage
    RD_A(1);
    stage_half(BT, col0 + 128, ldb, kbn, sm + 24576, w, lane);  // BH <- t+1
    BAR(); MM(1, 1, bF1); BAR();
    // ph4: quad(1,0) register-only (aF from ph3, bF0 from ph1); AH free -> restage
    stage_half(A, row0 + 128, lda, kan, sm + 8192, w, lane);    // AH <- t+1
    WAITVM(4);                                            // AL',BL' confirmed (BH',AH' in flight)
    BAR(); MM(1, 0, bF0); BAR();
  }
  WAITVM(0);   // drain tail loads before workgroup teardown

  // epilogue: f32 store, or f16 store (correction partial)
#pragma unroll
  for (int i = 0; i < 8; ++i) {
    int mh = i >> 2, m = i & 3;
#pragma unroll
    for (int j = 0; j < 4; ++j) {
      int nh = j >> 1, n = j & 1;
#pragma unroll
      for (int r = 0; r < 4; ++r) {
        int rr = row0 + mh * 128 + wm * 64 + m * 16 + quad * 4 + r;
        int cc = col0 + nh * 128 + wn * 32 + n * 16 + l15;
        if (Ch)
          Ch[(size_t)rr * ldch + cc] = f2h_bits(acc[i][j][r]);
        else
          C[(size_t)rr * ldc + cc] = acc[i][j][r];
      }
    }
  }
}

// ---- fused QKV projection, balanced 352-block grid, no atomics ----
__global__ __launch_bounds__(512) void k_gemm_qkv(const u16* __restrict__ A2, const u16* __restrict__ B2T,
                                                  const u16* __restrict__ WvT, float* __restrict__ qkv,
                                                  u16* __restrict__ corr) {
  __shared__ u16 sm[32768];   // 64KB
  int id = blockIdx.x;
  if (id < 160) {
    int row0 = (id / 10) * 256, col0 = (id % 10) * 256;
    gemm256(A2, B2T, nullptr, corr, sm, row0, col0, 64, 4096, 4096, 0, 2560, 0x01, 0x10, 0, 0);
  } else if (id < 320) {
    int t = id - 160;
    int row0 = (t / 10) * 256, col0 = (t % 10) * 256;
    gemm256(A2, B2T, qkv, nullptr, sm, row0, col0, 32, 4096, 4096, 3072, 0, 0, 0, 0, 0);
  } else {
    int t = id - 320;
    int row0 = (t >> 1) * 256, col0 = (t & 1) * 256;
    gemm256(A2, WvT, qkv + 2560, nullptr, sm, row0, col0, 32, 4096, 2048, 3072, 0, 0, 0, 0, 0);
  }
}

// ---- out = attn @ Wo, split-K=2: 256 uniform blocks (NT=16), p=0 -> out, p=1 -> P1; then k_add ----
__global__ __launch_bounds__(512) void k_gemm_wo(const u16* __restrict__ attn, const u16* __restrict__ WoT,
                                                 float* __restrict__ out, float* __restrict__ P1) {
  __shared__ u16 sm[32768];   // 64KB
  int id = blockIdx.x;
  int p = id >> 7, rem = id & 127;
  int row0 = (rem >> 3) * 256, col0 = (rem & 7) * 256;
  float* Cp = p ? P1 : out;
  gemm256(attn, WoT, Cp, nullptr, sm, row0, col0, 16, 2048, 2048, 2048, 0, 0, 0,
          p * 1024, p * 1024);
}

// ---- RoPE (+f16 correction add) + write q/k f16 + fp32 block means ----
__global__ __launch_bounds__(256) void k_rope_mean(const float* __restrict__ qkv, const u16* __restrict__ corr,
                                                   const float* __restrict__ cosb, const float* __restrict__ sinb,
                                                   u16* __restrict__ qbf, u16* __restrict__ kbf,
                                                   float* __restrict__ qblk, float* __restrict__ kblk) {
  int cc = blockIdx.x, i = blockIdx.y, b = blockIdx.z;
  int c = cc * 256 + threadIdx.x;          // 0..2559 (q cols 0..2047, k cols 2048..2559)
  bool isq = c < 2048;
  int hh = isq ? (c >> 7) : ((c - 2048) >> 7);
  int d = isq ? (c & 127) : ((c - 2048) & 127);
  int pairc = (d < 64) ? c + 64 : c - 64;
  float sgn = (d < 64) ? -1.0f : 1.0f;
  int row0 = b * S_ + i * 64;
  float sum = 0.0f;
  for (int s = 0; s < 64; ++s) {
    int row = row0 + s;
    float x1 = qkv[(size_t)row * 3072 + c]
             + (float)__builtin_bit_cast(_Float16, corr[(size_t)row * 2560 + c]);
    float x2 = qkv[(size_t)row * 3072 + pairc]
             + (float)__builtin_bit_cast(_Float16, corr[(size_t)row * 2560 + pairc]);
    float cv = cosb[(size_t)row * 128 + d];
    float sv = sinb[(size_t)row * 128 + d];
    float val = x1 * cv + sgn * x2 * sv;
    sum += val;
    if (isq)
      qbf[((size_t)(b * H_ + hh) * S_ + i * 64 + s) * 128 + d] = f2h_bits(val);
    else
      kbf[((size_t)(b * HKV_ + hh) * S_ + i * 64 + s) * 128 + d] = f2h_bits(val);
  }
  if (isq)
    qblk[((size_t)(b * H_ + hh) * NB_ + i) * 128 + d] = sum * 0.015625f;
  else
    kblk[((size_t)(b * HKV_ + hh) * NB_ + i) * 128 + d] = sum * 0.015625f;
}

// ---- V -> f16 transposed layout (B,HKV,D,S) ----
__global__ __launch_bounds__(256) void k_vlayout(const float* __restrict__ qkv, u16* __restrict__ vT) {
  int i = blockIdx.x, hk = blockIdx.y, b = blockIdx.z;
  __shared__ u16 tile[64 * 130];
#pragma unroll
  for (int p = 0; p < 32; ++p) {
    int e = threadIdx.x + p * 256;
    int s = e >> 7, d = e & 127;
    float v = qkv[(size_t)(b * S_ + i * 64 + s) * 3072 + 2560 + hk * 128 + d];
    tile[s * 130 + d] = f2h_bits(v);
  }
  __syncthreads();
#pragma unroll
  for (int p = 0; p < 32; ++p) {
    int e = threadIdx.x + p * 256;
    int d2 = e >> 6, s2 = e & 63;
    vT[((size_t)(b * HKV_ + hk) * 128 + d2) * S_ + i * 64 + s2] = tile[s2 * 130 + d2];
  }
}

// ---- gate mask: sigmoid(logit)>=0.5 <=> dot>=0; | eye; & tril ----
__global__ __launch_bounds__(256) void k_gate(const float* __restrict__ qblk, const float* __restrict__ kblk,
                                              int* __restrict__ mask) {
  int h = blockIdx.x, b = blockIdx.y;
  int hk = h >> 2;
  __shared__ float qs[32 * 128];
  __shared__ float ks[32 * 128];
  size_t qb0 = (size_t)(b * H_ + h) * NB_ * 128;
  size_t kb0 = (size_t)(b * HKV_ + hk) * NB_ * 128;
#pragma unroll
  for (int p = 0; p < 16; ++p) {
    int e = threadIdx.x + p * 256;
    qs[e] = qblk[qb0 + e];
    ks[e] = kblk[kb0 + e];
  }
  __syncthreads();
#pragma unroll
  for (int p = 0; p < 4; ++p) {
    int l = threadIdx.x + p * 256;
    int i = l >> 5, j = l & 31;
    int m;
    if (j > i) m = 0;
    else if (j == i) m = 1;
    else {
      float dot = 0.0f;
      for (int d = 0; d < 128; ++d) dot += qs[i * 128 + d] * ks[j * 128 + d];
      m = (dot >= 0.0f) ? 1 : 0;
    }
    mask[((size_t)(b * H_ + h) * NB_ + i) * NB_ + j] = m;
  }
}

// ---- block-sparse flash attention, static-max softmax, PIPELINED K/V staging ----
// Double-buffered Ks/Vs (72KB LDS, 2 blocks/CU); counted WAITVM(8) drains only the CURRENT
// tile's 8 loads while the next tile's 8 fly under compute (T4 lesson from the GEMM).
// Ledger: at loop top, outstanding = 8 (jcur's loads). Stage(jn)->16; WAITVM(8)->jcur done.
// Same tile order as before -> bit-identical output. Heavy blocks (large i) dispatched first.
__global__ __launch_bounds__(256) void k_flash(const u16* __restrict__ qbf, const u16* __restrict__ kbf,
                                               const u16* __restrict__ vT, const int* __restrict__ mask,
                                               u16* __restrict__ attn) {
  const int id = blockIdx.x;
  const int i = 31 - (id >> 5);     // reverse: heavy rows first for makespan
  const int hb = id & 31;
  const int h = hb & 15, b = hb >> 4;
  const int hk = h >> 2;
  const int tid = threadIdx.x;
  const int lane = tid & 63;
  const int w = tid >> 6;
  const int quad = lane >> 4;
  const int l15 = lane & 15;

  __shared__ u16 Ksb[2 * 64 * 128];  // [buf][tok][d], swizzle u_phys = u ^ (tok&15)
  __shared__ u16 Vsb[2 * 128 * 64];  // [buf][d][tok], swizzle u_phys = u ^ (dd&7)
  __shared__ u16 Ps[4 * 16 * 64];    // per-wave [m][k]

  half8 qF[4];
  const u16* qbase = qbf + ((size_t)(b * H_ + h) * S_ + i * 64 + w * 16 + l15) * 128;
#pragma unroll
  for (int kk = 0; kk < 4; ++kk)
    qF[kk] = *reinterpret_cast<const half8*>(qbase + kk * 32 + quad * 8);

  floatx4 o[8];
#pragma unroll
  for (int t = 0; t < 8; ++t) o[t] = (floatx4){0.f, 0.f, 0.f, 0.f};
  float ls[4] = {0.f, 0.f, 0.f, 0.f};

  const u16* kb = kbf + (size_t)(b * HKV_ + hk) * S_ * 128;
  const u16* vb = vT + (size_t)(b * HKV_ + hk) * 128 * S_;
  const int* mrp = mask + ((size_t)(b * H_ + h) * NB_ + i) * NB_;

#define FSTAGE(J, BUF) do { \
  _Pragma("unroll") \
  for (int t_ = 0; t_ < 4; ++t_) { \
    int g2 = t_ * 4 + w; \
    int stok = g2 * 4 + (lane >> 4); \
    int ul = (lane & 15) ^ (stok & 15); \
    const u16* srcK = kb + (size_t)((J) * 64 + stok) * 128 + ul * 8; \
    __builtin_amdgcn_global_load_lds((const __attribute__((address_space(1))) unsigned int*)srcK, \
                                     (__attribute__((address_space(3))) unsigned int*)(Ksb + (BUF) * 8192 + g2 * 512), \
                                     16, 0, 0); \
    int sdd = g2 * 8 + (lane >> 3); \
    int ulv = (lane & 7) ^ (sdd & 7); \
    const u16* srcV = vb + (size_t)sdd * S_ + (J) * 64 + ulv * 8; \
    __builtin_amdgcn_global_load_lds((const __attribute__((address_space(1))) unsigned int*)srcV, \
                                     (__attribute__((address_space(3))) unsigned int*)(Vsb + (BUF) * 8192 + g2 * 512), \
                                     16, 0, 0); \
  } } while (0)

  int jcur = 0;
  while (!mrp[jcur]) ++jcur;        // diag guarantees jcur <= i
  FSTAGE(jcur, 0);                  // prologue: 8 loads in flight
  int cur = 0;

  for (;;) {
    int jn = jcur + 1;
    while (jn <= i && !mrp[jn]) ++jn;
    bool hn = (jn <= i);
    if (hn) { FSTAGE(jn, cur ^ 1); WAITVM(8); }   // jcur's 8 done; jn's 8 in flight
    else    { WAITVM(0); }
    BAR();                                        // all waves' jcur loads landed

    const u16* Kc = Ksb + cur * 8192;
    const u16* Vc = Vsb + cur * 8192;
#pragma unroll
    for (int ct = 0; ct < 4; ++ct) {
      floatx4 cacc = (floatx4){0.f, 0.f, 0.f, 0.f};
#pragma unroll
      for (int kk = 0; kk < 4; ++kk) {
        int phys = (kk * 4 + quad) ^ l15;
        half8 bF = *reinterpret_cast<const half8*>(&Kc[(ct * 16 + l15) * 128 + phys * 8]);
        cacc = __builtin_amdgcn_mfma_f32_16x16x32_f16(qF[kk], bF, cacc, 0, 0, 0);
      }
#pragma unroll
      for (int r = 0; r < 4; ++r) {
        float s = cacc[r];
        if (jcur == i && (ct * 16 + l15) > (w * 16 + quad * 4 + r)) s = -1e30f;
        float p = __builtin_exp2f(fmaf(s, SC_L2, -SMAX_L2));
        _Float16 ph = (_Float16)p;           // quantize ONCE; numerator and
        ls[r] += (float)ph;                  // denominator see the same value
        Ps[w * 1024 + (quad * 4 + r) * 64 + ct * 16 + l15] = __builtin_bit_cast(u16, ph);
      }
    }
#pragma unroll
    for (int kk2 = 0; kk2 < 2; ++kk2) {
      half8 aP = *reinterpret_cast<const half8*>(&Ps[w * 1024 + l15 * 64 + kk2 * 32 + quad * 8]);
#pragma unroll
      for (int ct2 = 0; ct2 < 8; ++ct2) {
        int phys = (kk2 * 4 + quad) ^ (l15 & 7);
        half8 bV = *reinterpret_cast<const half8*>(&Vc[(ct2 * 16 + l15) * 64 + phys * 8]);
        o[ct2] = __builtin_amdgcn_mfma_f32_16x16x32_f16(aP, bV, o[ct2], 0, 0, 0);
      }
    }
    BAR();                                        // all waves done reading cur before restage
    if (!hn) break;
    jcur = jn; cur ^= 1;
  }

#pragma unroll
  for (int xm = 1; xm < 16; xm <<= 1)
#pragma unroll
    for (int r = 0; r < 4; ++r) ls[r] += __shfl_xor(ls[r], xm, 64);
  float invl[4];
#pragma unroll
  for (int r = 0; r < 4; ++r) invl[r] = 1.0f / ls[r];
#pragma unroll
  for (int ct2 = 0; ct2 < 8; ++ct2)
#pragma unroll
    for (int r = 0; r < 4; ++r) {
      size_t row = (size_t)(b * S_ + i * 64 + w * 16 + quad * 4 + r);
      attn[row * 2048 + h * 128 + ct2 * 16 + l15] = f2h_bits(o[ct2][r] * invl[r]);
    }
}

extern "C" void kernel_launch(void* const* d_in, const int* in_sizes, int n_in,
                              void* d_out, int out_size, void* d_ws, size_t ws_size,
                              hipStream_t stream) {
  const float* hs = (const float*)d_in[0];
  const float* cosb = (const float*)d_in[1];
  const float* sinb = (const float*)d_in[2];
  const float* Wq = (const float*)d_in[3];
  const float* Wk = (const float*)d_in[4];
  const float* Wv = (const float*)d_in[5];
  const float* Wo = (const float*)d_in[6];
  float* out = (float*)d_out;
  char* ws = (char*)d_ws;

  // phase-1 buffers
  u16* A2 = (u16*)(ws + 0);               // 4096x4096 f16 (hs splits [s0|s1])        [0, 33.5M)
  u16* B2T = (u16*)(ws + 33554432);       // 2560x4096 f16 ([WqT;WkT] splits [t0|t1]) [33.5M, 54.5M)
  u16* WvT = (u16*)(ws + 54525952);       // 512x2048 f16                             [54.5M, 56.6M)
  float* qkv = (float*)(ws + 56623104);   // 4096x3072 f32                            [56.6M, 107M)
  u16* corr = (u16*)out;                  // 4096x2560 f16 correction partial -- d_out is dead
                                          // until k_gemm_wo overwrites it at the very end
  // phase-2 aliases (dead GEMM inputs reused)
  u16* attn = (u16*)(ws + 0);             // 4096x2048 f16  (in dead A2)
  u16* qbf = (u16*)(ws + 16777216);       // (in dead A2)
  u16* kbf = (u16*)(ws + 33554432);       // (in dead B2T)
  u16* vTbf = (u16*)(ws + 37748736);
  float* qblk = (float*)(ws + 41943040);
  float* kblk = (float*)(ws + 42467328);
  int* mask = (int*)(ws + 42598400);
  u16* WoT = (u16*)(ws + 43122688);       // 2048x2048 f16  (in dead B2T; written after QK GEMM)
  float* P1 = (float*)(ws + 56623104);    // 4096x2048 f32 split-K partial (in dead qkv region)

  (void)in_sizes; (void)n_in; (void)out_size; (void)ws_size;

  // fused prep: split_hs + Wq/Wk/Wv transposes (one launch)
  k_prep<<<9728, 256, 0, stream>>>(hs, A2, Wq, Wk, Wv, B2T, WvT);

  // QKV: balanced 352 blocks (corr NT=64 first; main + V NT=32 backfill); no atomics
  k_gemm_qkv<<<352, 512, 0, stream>>>(A2, B2T, WvT, qkv, corr);

  // Wo transpose into dead B2T space (after QK GEMM consumed B2T)
  k_transpose_split<<<dim3(32, 32), 256, 0, stream>>>(Wo, WoT, 2048, 2048, 2048, 1);

  // RoPE (+corr add) + f16 q/k + fp32 block means; V layout
  k_rope_mean<<<dim3(10, 32, 2), 256, 0, stream>>>(qkv, corr, cosb, sinb, qbf, kbf, qblk, kblk);
  k_vlayout<<<dim3(32, 4, 2), 256, 0, stream>>>(qkv, vTbf);

  // gate mask
  k_gate<<<dim3(16, 2), 256, 0, stream>>>(qblk, kblk, mask);

  // block-sparse flash attention (pipelined K/V double-buffer, counted vmcnt)
  k_flash<<<1024, 256, 0, stream>>>(qbf, kbf, vTbf, mask, attn);

  // out = attn @ Wo: split-K=2, 256 uniform blocks (full chip), then reduce
  k_gemm_wo<<<256, 512, 0, stream>>>(attn, WoT, out, P1);
  k_add<<<8192, 256, 0, stream>>>((float4*)out, (const float4*)P1);
}

// Round 11
// 388.484 us; speedup vs baseline: 1.1409x; 1.0425x over previous
//
#include <hip/hip_runtime.h>
#include <stdint.h>

typedef unsigned short u16;
typedef _Float16 half8 __attribute__((ext_vector_type(8)));
typedef float floatx4 __attribute__((ext_vector_type(4)));
typedef u16 u16x4 __attribute__((ext_vector_type(4)));

#define B_ 2
#define S_ 2048
#define HID_ 2048
#define H_ 16
#define HKV_ 4
#define D_ 128
#define NB_ 32
#define SCALE_ 0.08838834764831845f
// p = exp(s*SCALE - 4) == exp2(fma(s, SC_L2, -SMAX_L2))
#define SC_L2 0.12753102331884178f
#define SMAX_L2 5.770780163555852f

__device__ __forceinline__ u16 f2h_bits(float f) {
  _Float16 h = (_Float16)f;
  return __builtin_bit_cast(u16, h);
}

// ---- transpose body: W (Kdim x N) tile -> dst rows n: [split0 K | split1 K ...], f16 ----
__device__ __forceinline__ void transpose_body(const float* __restrict__ src, u16* __restrict__ dst,
                                               int Kdim, int N, int ldd, int nsplit,
                                               int k0, int n0, float (*tile)[65]) {
#pragma unroll
  for (int p = 0; p < 16; ++p) {
    int e = threadIdx.x + p * 256;
    int r = e >> 6, c = e & 63;
    tile[r][c] = src[(size_t)(k0 + r) * N + n0 + c];
  }
  __syncthreads();
#pragma unroll
  for (int p = 0; p < 16; ++p) {
    int e = threadIdx.x + p * 256;
    int k = e & 63, n = e >> 6;
    float v = tile[k][n];
    for (int s = 0; s < nsplit; ++s) {
      _Float16 hh = (_Float16)v;
      dst[(size_t)(n0 + n) * ldd + s * Kdim + k0 + k] = __builtin_bit_cast(u16, hh);
      v -= (float)hh;
    }
  }
}

// ---- fused prep: split_hs (8192 blocks) + Wq (1024) + Wk (256) + Wv (256) transposes ----
__global__ __launch_bounds__(256) void k_prep(const float* __restrict__ hs, u16* __restrict__ A2,
                                              const float* __restrict__ Wq, const float* __restrict__ Wk,
                                              const float* __restrict__ Wv,
                                              u16* __restrict__ B2T, u16* __restrict__ WvT) {
  __shared__ float tile[64][65];
  int id = blockIdx.x;
  if (id < 8192) {
    int idx = id * 256 + threadIdx.x;
    int f0 = idx * 4;
    float4 v = *reinterpret_cast<const float4*>(hs + f0);
    float vv[4] = {v.x, v.y, v.z, v.w};
    u16x4 h0, h1;
#pragma unroll
    for (int e = 0; e < 4; ++e) {
      _Float16 a = (_Float16)vv[e];
      float r = vv[e] - (float)a;
      _Float16 b = (_Float16)r;
      h0[e] = __builtin_bit_cast(u16, a);
      h1[e] = __builtin_bit_cast(u16, b);
    }
    int row = f0 >> 11;
    int col = f0 & 2047;
    *reinterpret_cast<u16x4*>(A2 + (size_t)row * 4096 + col) = h0;
    *reinterpret_cast<u16x4*>(A2 + (size_t)row * 4096 + 2048 + col) = h1;
  } else if (id < 9216) {
    int t = id - 8192;
    transpose_body(Wq, B2T, 2048, 2048, 4096, 2, (t & 31) * 64, (t >> 5) * 64, tile);
  } else if (id < 9472) {
    int t = id - 9216;
    transpose_body(Wk, B2T + (size_t)2048 * 4096, 2048, 512, 4096, 2, (t & 31) * 64, (t >> 5) * 64, tile);
  } else {
    int t = id - 9472;
    transpose_body(Wv, WvT, 2048, 512, 2048, 1, (t & 31) * 64, (t >> 5) * 64, tile);
  }
}

// ---- standalone transpose (Wo, must run after QK GEMM) ----
__global__ __launch_bounds__(256) void k_transpose_split(const float* __restrict__ src, u16* __restrict__ dst,
                                                         int Kdim, int N, int ldd, int nsplit) {
  __shared__ float tile[64][65];
  transpose_body(src, dst, Kdim, N, ldd, nsplit, blockIdx.x * 64, blockIdx.y * 64, tile);
}

// ============ 256x256 GEMM, BK=64, 4-half LDS ring, counted vmcnt (64KB static LDS) ============
// (round-7-proven form; round-8's drain-0 double-buffer regressed — T4 confirmed on this kernel)
// Ledger (2 loads per stage_half per thread), invariant entering ph1: 4.
//   ph1: RD AL,BL            ; wait vmcnt(2)  [drains BH(t);  AH(t) in flight]
//   ph2: RD BH ; stage AL',BL'; wait vmcnt(4) [drains AH(t);  AL'BL' in flight]
//   ph3: RD AH ; stage BH'    ; (no wait)
//   ph4: stage AH'            ; wait vmcnt(4) [drains AL'BL'; BH'AH' in flight]

#define FENCE() __builtin_amdgcn_sched_barrier(0)
#define BAR() do { FENCE(); __builtin_amdgcn_s_barrier(); FENCE(); } while (0)
#define WAITVM(N) do { FENCE(); asm volatile("s_waitcnt vmcnt(" #N ")" ::: "memory"); FENCE(); } while (0)

__device__ __forceinline__ int kmap(int map, int t) {
  return ((map >> ((t >> 5) * 4)) & 15) * 2048 + (t & 31) * 64;
}

__device__ __forceinline__ void stage_half(const u16* __restrict__ src, int sr0, int lda, int kb,
                                           u16* dst, int w, int lane) {
#pragma unroll
  for (int rr = 0; rr < 2; ++rr) {
    int chunk = rr * 8 + w;                  // 0..15, wave-uniform
    int row = chunk * 8 + (lane >> 3);       // 0..127
    int slot = (lane & 7) ^ (lane >> 3);     // inverse swizzle (row&7 == lane>>3)
    const u16* gp = src + (size_t)(sr0 + row) * lda + kb + slot * 8;
    __builtin_amdgcn_global_load_lds((const __attribute__((address_space(1))) unsigned int*)gp,
                                     (__attribute__((address_space(3))) unsigned int*)(dst + chunk * 512),
                                     16, 0, 0);
  }
}

#define RD_A(mh) do { \
  _Pragma("unroll") \
  for (int m_ = 0; m_ < 4; ++m_) { \
    aF[m_][0] = *reinterpret_cast<const half8*>(&sm[(mh)*8192 + (wm*64 + m_*16 + l15)*64 + ((quad ^ l7) * 8)]); \
    aF[m_][1] = *reinterpret_cast<const half8*>(&sm[(mh)*8192 + (wm*64 + m_*16 + l15)*64 + (((4 + quad) ^ l7) * 8)]); \
  } } while (0)

#define RD_B(nh, BF) do { \
  _Pragma("unroll") \
  for (int n_ = 0; n_ < 2; ++n_) { \
    BF[n_][0] = *reinterpret_cast<const half8*>(&sm[16384 + (nh)*8192 + (wn*32 + n_*16 + l15)*64 + ((quad ^ l7) * 8)]); \
    BF[n_][1] = *reinterpret_cast<const half8*>(&sm[16384 + (nh)*8192 + (wn*32 + n_*16 + l15)*64 + (((4 + quad) ^ l7) * 8)]); \
  } } while (0)

#define MM(mh, nh, BF) do { \
  __builtin_amdgcn_s_setprio(1); \
  _Pragma("unroll") \
  for (int m_ = 0; m_ < 4; ++m_) \
  _Pragma("unroll") \
  for (int n_ = 0; n_ < 2; ++n_) { \
    acc[(mh)*4 + m_][(nh)*2 + n_] = __builtin_amdgcn_mfma_f32_16x16x32_f16(aF[m_][0], BF[n_][0], acc[(mh)*4 + m_][(nh)*2 + n_], 0, 0, 0); \
    acc[(mh)*4 + m_][(nh)*2 + n_] = __builtin_amdgcn_mfma_f32_16x16x32_f16(aF[m_][1], BF[n_][1], acc[(mh)*4 + m_][(nh)*2 + n_], 0, 0, 0); \
  } \
  __builtin_amdgcn_s_setprio(0); } while (0)

__device__ __forceinline__ void gemm256(const u16* __restrict__ A, const u16* __restrict__ BT,
                                        float* __restrict__ C, u16* __restrict__ Ch, u16* sm,
                                        int row0, int col0, int NT,
                                        int lda, int ldb, int ldc, int ldch,
                                        int amap, int bmap) {
  const int tid = (int)threadIdx.x;
  const int lane = tid & 63;
  const int w = tid >> 6;
  const int wm = w >> 2, wn = w & 3;
  const int quad = lane >> 4, l15 = lane & 15, l7 = lane & 7;

  floatx4 acc[8][4];
#pragma unroll
  for (int i = 0; i < 8; ++i)
#pragma unroll
    for (int j = 0; j < 4; ++j) acc[i][j] = (floatx4){0.f, 0.f, 0.f, 0.f};

  half8 aF[4][2], bF0[2][2], bF1[2][2];

  // prologue: stage tile 0 (AL,BL oldest so vmcnt(4) drains them first)
  {
    int ka = kmap(amap, 0), kb = kmap(bmap, 0);
    stage_half(A,  row0,       lda, ka, sm + 0,     w, lane);  // AL
    stage_half(BT, col0,       ldb, kb, sm + 16384, w, lane);  // BL
    stage_half(BT, col0 + 128, ldb, kb, sm + 24576, w, lane);  // BH
    stage_half(A,  row0 + 128, lda, ka, sm + 8192,  w, lane);  // AH
  }
  WAITVM(4);   // own AL,BL landed; BH,AH in flight
  BAR();       // all waves' AL,BL landed before any ds_read

  for (int t = 0; t < NT; ++t) {
    int tn = t + 1; if (tn >= NT) tn = 0;    // clamp keeps vmcnt counts uniform
    int kan = kmap(amap, tn), kbn = kmap(bmap, tn);

    // ph1: quad(0,0) reads AL,BL
    RD_A(0); RD_B(0, bF0);
    WAITVM(2);                                            // BH(t) confirmed (AH in flight)
    BAR(); MM(0, 0, bF0); BAR();
    // ph2: quad(0,1) reads BH; AL,BL free -> restage for t+1
    RD_B(1, bF1);
    stage_half(A,  row0, lda, kan, sm + 0,     w, lane);  // AL <- t+1
    stage_half(BT, col0, ldb, kbn, sm + 16384, w, lane);  // BL <- t+1
    WAITVM(4);                                            // AH(t) confirmed (AL',BL' in flight)
    BAR(); MM(0, 1, bF1); BAR();
    // ph3: quad(1,1) reads AH; BH free -> restage
    RD_A(1);
    stage_half(BT, col0 + 128, ldb, kbn, sm + 24576, w, lane);  // BH <- t+1
    BAR(); MM(1, 1, bF1); BAR();
    // ph4: quad(1,0) register-only (aF from ph3, bF0 from ph1); AH free -> restage
    stage_half(A, row0 + 128, lda, kan, sm + 8192, w, lane);    // AH <- t+1
    WAITVM(4);                                            // AL',BL' confirmed (BH',AH' in flight)
    BAR(); MM(1, 0, bF0); BAR();
  }
  WAITVM(0);   // drain tail loads before workgroup teardown

  // epilogue: f32 store, or f16 store (correction partial)
#pragma unroll
  for (int i = 0; i < 8; ++i) {
    int mh = i >> 2, m = i & 3;
#pragma unroll
    for (int j = 0; j < 4; ++j) {
      int nh = j >> 1, n = j & 1;
#pragma unroll
      for (int r = 0; r < 4; ++r) {
        int rr = row0 + mh * 128 + wm * 64 + m * 16 + quad * 4 + r;
        int cc = col0 + nh * 128 + wn * 32 + n * 16 + l15;
        if (Ch)
          Ch[(size_t)rr * ldch + cc] = f2h_bits(acc[i][j][r]);
        else
          C[(size_t)rr * ldc + cc] = acc[i][j][r];
      }
    }
  }
}

// ============ 128x256 GEMM variant (BM=128): 48KB LDS ring, re-derived ledger ============
// Halves: A-lo [0,4096) A-hi [4096,8192) (64 rows, 1 load/thread), B-lo [8192,16384)
// B-hi [16384,24576) (128 rows, 2 loads/thread). 8 waves = 2(M) x 4(N); per-wave 64x64.
// Ledger (loads/thread: A=1, B=2). Prologue AL(1),BL(2),BH(2),AH(1)=6; WAITVM(3) leaves
// BH(2)+AH(1) [oldest-first drain of AL,BL]. Invariant entering ph1: 3.
//   ph1: RD AL,BL             ; WAITVM(1) [drains BH;   AH in flight]
//   ph2: RD BH ; stage AL'(1),BL'(2) -> 4 ; WAITVM(3) [drains AH]
//   ph3: RD AH ; stage BH'(2) -> 5 ; (no wait)
//   ph4: stage AH'(1) -> 6    ; WAITVM(3) [drains AL',BL'; leaves BH'+AH' = invariant]

__device__ __forceinline__ void stage_halfA64(const u16* __restrict__ src, int sr0, int lda, int kb,
                                              u16* dst, int w, int lane) {
  int row = w * 8 + (lane >> 3);             // 0..63
  int slot = (lane & 7) ^ (lane >> 3);       // row&7 == lane>>3
  const u16* gp = src + (size_t)(sr0 + row) * lda + kb + slot * 8;
  __builtin_amdgcn_global_load_lds((const __attribute__((address_space(1))) unsigned int*)gp,
                                   (__attribute__((address_space(3))) unsigned int*)(dst + w * 512),
                                   16, 0, 0);
}

#define RD_A128(mh) do { \
  _Pragma("unroll") \
  for (int m_ = 0; m_ < 2; ++m_) { \
    aF[m_][0] = *reinterpret_cast<const half8*>(&sm[(mh)*4096 + (wm*32 + m_*16 + l15)*64 + ((quad ^ l7) * 8)]); \
    aF[m_][1] = *reinterpret_cast<const half8*>(&sm[(mh)*4096 + (wm*32 + m_*16 + l15)*64 + (((4 + quad) ^ l7) * 8)]); \
  } } while (0)

#define RD_B128(nh, BF) do { \
  _Pragma("unroll") \
  for (int n_ = 0; n_ < 2; ++n_) { \
    BF[n_][0] = *reinterpret_cast<const half8*>(&sm[8192 + (nh)*8192 + (wn*32 + n_*16 + l15)*64 + ((quad ^ l7) * 8)]); \
    BF[n_][1] = *reinterpret_cast<const half8*>(&sm[8192 + (nh)*8192 + (wn*32 + n_*16 + l15)*64 + (((4 + quad) ^ l7) * 8)]); \
  } } while (0)

#define MM128(mh, nh, BF) do { \
  __builtin_amdgcn_s_setprio(1); \
  _Pragma("unroll") \
  for (int m_ = 0; m_ < 2; ++m_) \
  _Pragma("unroll") \
  for (int n_ = 0; n_ < 2; ++n_) { \
    acc[(mh)*2 + m_][(nh)*2 + n_] = __builtin_amdgcn_mfma_f32_16x16x32_f16(aF[m_][0], BF[n_][0], acc[(mh)*2 + m_][(nh)*2 + n_], 0, 0, 0); \
    acc[(mh)*2 + m_][(nh)*2 + n_] = __builtin_amdgcn_mfma_f32_16x16x32_f16(aF[m_][1], BF[n_][1], acc[(mh)*2 + m_][(nh)*2 + n_], 0, 0, 0); \
  } \
  __builtin_amdgcn_s_setprio(0); } while (0)

__device__ __forceinline__ void gemm128(const u16* __restrict__ A, const u16* __restrict__ BT,
                                        float* __restrict__ C, u16* sm,
                                        int row0, int col0, int NT,
                                        int lda, int ldb, int ldc) {
  const int tid = (int)threadIdx.x;
  const int lane = tid & 63;
  const int w = tid >> 6;
  const int wm = w >> 2, wn = w & 3;
  const int quad = lane >> 4, l15 = lane & 15, l7 = lane & 7;

  floatx4 acc[4][4];
#pragma unroll
  for (int i = 0; i < 4; ++i)
#pragma unroll
    for (int j = 0; j < 4; ++j) acc[i][j] = (floatx4){0.f, 0.f, 0.f, 0.f};

  half8 aF[2][2], bF0[2][2], bF1[2][2];

  // prologue
  stage_halfA64(A,  row0,      lda, 0, sm + 0,     w, lane);  // AL (1)
  stage_half  (BT, col0,       ldb, 0, sm + 8192,  w, lane);  // BL (2)
  stage_half  (BT, col0 + 128, ldb, 0, sm + 16384, w, lane);  // BH (2)
  stage_halfA64(A,  row0 + 64, lda, 0, sm + 4096,  w, lane);  // AH (1)
  WAITVM(3);
  BAR();

  for (int t = 0; t < NT; ++t) {
    int tn = t + 1; if (tn >= NT) tn = 0;
    int kn = tn * 64;

    // ph1: quad(0,0) reads AL,BL
    RD_A128(0); RD_B128(0, bF0);
    WAITVM(1);                                              // BH confirmed (AH in flight)
    BAR(); MM128(0, 0, bF0); BAR();
    // ph2: quad(0,1) reads BH; restage AL,BL
    RD_B128(1, bF1);
    stage_halfA64(A,  row0, lda, kn, sm + 0,    w, lane);   // AL' (1)
    stage_half  (BT, col0, ldb, kn, sm + 8192,  w, lane);   // BL' (2)
    WAITVM(3);                                              // AH confirmed
    BAR(); MM128(0, 1, bF1); BAR();
    // ph3: quad(1,1) reads AH; restage BH
    RD_A128(1);
    stage_half(BT, col0 + 128, ldb, kn, sm + 16384, w, lane); // BH' (2)
    BAR(); MM128(1, 1, bF1); BAR();
    // ph4: quad(1,0) register-only; restage AH
    stage_halfA64(A, row0 + 64, lda, kn, sm + 4096, w, lane); // AH' (1)
    WAITVM(3);                                              // AL',BL' confirmed
    BAR(); MM128(1, 0, bF0); BAR();
  }
  WAITVM(0);

#pragma unroll
  for (int i = 0; i < 4; ++i) {
    int mh = i >> 1, m = i & 1;
#pragma unroll
    for (int j = 0; j < 4; ++j) {
      int nh = j >> 1, n = j & 1;
#pragma unroll
      for (int r = 0; r < 4; ++r) {
        int rr = row0 + mh * 64 + wm * 32 + m * 16 + quad * 4 + r;
        int cc = col0 + nh * 128 + wn * 32 + n * 16 + l15;
        C[(size_t)rr * ldc + cc] = acc[i][j][r];
      }
    }
  }
}

// ---- fused QKV projection, balanced 352-block grid, no atomics ----
// Physical ids 0..159 = correction (NT=64, dispatched first -> 1/CU at t=0);
// 160..319 = main QK (NT=32); 320..351 = V (NT=32).
// XCD-chunked swizzle WITHIN each 160-band: logical = (p%8)*20 + p/8 (bijective) so the
// 10 blocks sharing one A row-panel land on <=2 XCDs (panel L2 reuse) instead of all 8.
__global__ __launch_bounds__(512) void k_gemm_qkv(const u16* __restrict__ A2, const u16* __restrict__ B2T,
                                                  const u16* __restrict__ WvT, float* __restrict__ qkv,
                                                  u16* __restrict__ corr) {
  __shared__ u16 sm[32768];   // 64KB
  int id = blockIdx.x;
  if (id < 160) {
    int lg = (id & 7) * 20 + (id >> 3);          // XCD-chunk: 2 row-panels per XCD
    int row0 = (lg / 10) * 256, col0 = (lg % 10) * 256;
    gemm256(A2, B2T, nullptr, corr, sm, row0, col0, 64, 4096, 4096, 0, 2560, 0x01, 0x10);
  } else if (id < 320) {
    int t = id - 160;
    int lg = (t & 7) * 20 + (t >> 3);
    int row0 = (lg / 10) * 256, col0 = (lg % 10) * 256;
    gemm256(A2, B2T, qkv, nullptr, sm, row0, col0, 32, 4096, 4096, 3072, 0, 0, 0);
  } else {
    int t = id - 320;
    int row0 = (t >> 1) * 256, col0 = (t & 1) * 256;
    gemm256(A2, WvT, qkv + 2560, nullptr, sm, row0, col0, 32, 4096, 2048, 3072, 0, 0, 0);
  }
}

// ---- out = attn @ Wo: 256 blocks of 128x256, full K, full-chip balance, no reduction ----
__global__ __launch_bounds__(512) void k_gemm_wo(const u16* __restrict__ attn, const u16* __restrict__ WoT,
                                                 float* __restrict__ out) {
  __shared__ u16 sm[24576];   // 48KB
  int id = blockIdx.x;
  gemm128(attn, WoT, out, sm, (id >> 3) * 128, (id & 7) * 256, 32, 2048, 2048, 2048);
}

// ---- RoPE (+f16 correction add) + write q/k f16 + fp32 block means ----
__global__ __launch_bounds__(256) void k_rope_mean(const float* __restrict__ qkv, const u16* __restrict__ corr,
                                                   const float* __restrict__ cosb, const float* __restrict__ sinb,
                                                   u16* __restrict__ qbf, u16* __restrict__ kbf,
                                                   float* __restrict__ qblk, float* __restrict__ kblk) {
  int cc = blockIdx.x, i = blockIdx.y, b = blockIdx.z;
  int c = cc * 256 + threadIdx.x;          // 0..2559 (q cols 0..2047, k cols 2048..2559)
  bool isq = c < 2048;
  int hh = isq ? (c >> 7) : ((c - 2048) >> 7);
  int d = isq ? (c & 127) : ((c - 2048) & 127);
  int pairc = (d < 64) ? c + 64 : c - 64;
  float sgn = (d < 64) ? -1.0f : 1.0f;
  int row0 = b * S_ + i * 64;
  float sum = 0.0f;
  for (int s = 0; s < 64; ++s) {
    int row = row0 + s;
    float x1 = qkv[(size_t)row * 3072 + c]
             + (float)__builtin_bit_cast(_Float16, corr[(size_t)row * 2560 + c]);
    float x2 = qkv[(size_t)row * 3072 + pairc]
             + (float)__builtin_bit_cast(_Float16, corr[(size_t)row * 2560 + pairc]);
    float cv = cosb[(size_t)row * 128 + d];
    float sv = sinb[(size_t)row * 128 + d];
    float val = x1 * cv + sgn * x2 * sv;
    sum += val;
    if (isq)
      qbf[((size_t)(b * H_ + hh) * S_ + i * 64 + s) * 128 + d] = f2h_bits(val);
    else
      kbf[((size_t)(b * HKV_ + hh) * S_ + i * 64 + s) * 128 + d] = f2h_bits(val);
  }
  if (isq)
    qblk[((size_t)(b * H_ + hh) * NB_ + i) * 128 + d] = sum * 0.015625f;
  else
    kblk[((size_t)(b * HKV_ + hh) * NB_ + i) * 128 + d] = sum * 0.015625f;
}

// ---- V -> f16 transposed layout (B,HKV,D,S) ----
__global__ __launch_bounds__(256) void k_vlayout(const float* __restrict__ qkv, u16* __restrict__ vT) {
  int i = blockIdx.x, hk = blockIdx.y, b = blockIdx.z;
  __shared__ u16 tile[64 * 130];
#pragma unroll
  for (int p = 0; p < 32; ++p) {
    int e = threadIdx.x + p * 256;
    int s = e >> 7, d = e & 127;
    float v = qkv[(size_t)(b * S_ + i * 64 + s) * 3072 + 2560 + hk * 128 + d];
    tile[s * 130 + d] = f2h_bits(v);
  }
  __syncthreads();
#pragma unroll
  for (int p = 0; p < 32; ++p) {
    int e = threadIdx.x + p * 256;
    int d2 = e >> 6, s2 = e & 63;
    vT[((size_t)(b * HKV_ + hk) * 128 + d2) * S_ + i * 64 + s2] = tile[s2 * 130 + d2];
  }
}

// ---- gate mask: sigmoid(logit)>=0.5 <=> dot>=0; | eye; & tril ----
__global__ __launch_bounds__(256) void k_gate(const float* __restrict__ qblk, const float* __restrict__ kblk,
                                              int* __restrict__ mask) {
  int h = blockIdx.x, b = blockIdx.y;
  int hk = h >> 2;
  __shared__ float qs[32 * 128];
  __shared__ float ks[32 * 128];
  size_t qb0 = (size_t)(b * H_ + h) * NB_ * 128;
  size_t kb0 = (size_t)(b * HKV_ + hk) * NB_ * 128;
#pragma unroll
  for (int p = 0; p < 16; ++p) {
    int e = threadIdx.x + p * 256;
    qs[e] = qblk[qb0 + e];
    ks[e] = kblk[kb0 + e];
  }
  __syncthreads();
#pragma unroll
  for (int p = 0; p < 4; ++p) {
    int l = threadIdx.x + p * 256;
    int i = l >> 5, j = l & 31;
    int m;
    if (j > i) m = 0;
    else if (j == i) m = 1;
    else {
      float dot = 0.0f;
      for (int d = 0; d < 128; ++d) dot += qs[i * 128 + d] * ks[j * 128 + d];
      m = (dot >= 0.0f) ? 1 : 0;
    }
    mask[((size_t)(b * H_ + h) * NB_ + i) * NB_ + j] = m;
  }
}

// ---- block-sparse flash attention, static-max softmax, PIPELINED K/V staging ----
// Double-buffered Ks/Vs (72KB LDS); counted WAITVM(8) drains only the CURRENT tile's 8
// loads while the next tile's 8 fly under compute. Heavy blocks (large i) dispatched first.
__global__ __launch_bounds__(256) void k_flash(const u16* __restrict__ qbf, const u16* __restrict__ kbf,
                                               const u16* __restrict__ vT, const int* __restrict__ mask,
                                               u16* __restrict__ attn) {
  const int id = blockIdx.x;
  const int i = 31 - (id >> 5);     // reverse: heavy rows first for makespan
  const int hb = id & 31;
  const int h = hb & 15, b = hb >> 4;
  const int hk = h >> 2;
  const int tid = threadIdx.x;
  const int lane = tid & 63;
  const int w = tid >> 6;
  const int quad = lane >> 4;
  const int l15 = lane & 15;

  __shared__ u16 Ksb[2 * 64 * 128];  // [buf][tok][d], swizzle u_phys = u ^ (tok&15)
  __shared__ u16 Vsb[2 * 128 * 64];  // [buf][d][tok], swizzle u_phys = u ^ (dd&7)
  __shared__ u16 Ps[4 * 16 * 64];    // per-wave [m][k]

  half8 qF[4];
  const u16* qbase = qbf + ((size_t)(b * H_ + h) * S_ + i * 64 + w * 16 + l15) * 128;
#pragma unroll
  for (int kk = 0; kk < 4; ++kk)
    qF[kk] = *reinterpret_cast<const half8*>(qbase + kk * 32 + quad * 8);

  floatx4 o[8];
#pragma unroll
  for (int t = 0; t < 8; ++t) o[t] = (floatx4){0.f, 0.f, 0.f, 0.f};
  float ls[4] = {0.f, 0.f, 0.f, 0.f};

  const u16* kb = kbf + (size_t)(b * HKV_ + hk) * S_ * 128;
  const u16* vb = vT + (size_t)(b * HKV_ + hk) * 128 * S_;
  const int* mrp = mask + ((size_t)(b * H_ + h) * NB_ + i) * NB_;

#define FSTAGE(J, BUF) do { \
  _Pragma("unroll") \
  for (int t_ = 0; t_ < 4; ++t_) { \
    int g2 = t_ * 4 + w; \
    int stok = g2 * 4 + (lane >> 4); \
    int ul = (lane & 15) ^ (stok & 15); \
    const u16* srcK = kb + (size_t)((J) * 64 + stok) * 128 + ul * 8; \
    __builtin_amdgcn_global_load_lds((const __attribute__((address_space(1))) unsigned int*)srcK, \
                                     (__attribute__((address_space(3))) unsigned int*)(Ksb + (BUF) * 8192 + g2 * 512), \
                                     16, 0, 0); \
    int sdd = g2 * 8 + (lane >> 3); \
    int ulv = (lane & 7) ^ (sdd & 7); \
    const u16* srcV = vb + (size_t)sdd * S_ + (J) * 64 + ulv * 8; \
    __builtin_amdgcn_global_load_lds((const __attribute__((address_space(1))) unsigned int*)srcV, \
                                     (__attribute__((address_space(3))) unsigned int*)(Vsb + (BUF) * 8192 + g2 * 512), \
                                     16, 0, 0); \
  } } while (0)

  int jcur = 0;
  while (!mrp[jcur]) ++jcur;        // diag guarantees jcur <= i
  FSTAGE(jcur, 0);                  // prologue: 8 loads in flight
  int cur = 0;

  for (;;) {
    int jn = jcur + 1;
    while (jn <= i && !mrp[jn]) ++jn;
    bool hn = (jn <= i);
    if (hn) { FSTAGE(jn, cur ^ 1); WAITVM(8); }   // jcur's 8 done; jn's 8 in flight
    else    { WAITVM(0); }
    BAR();                                        // all waves' jcur loads landed

    const u16* Kc = Ksb + cur * 8192;
    const u16* Vc = Vsb + cur * 8192;
#pragma unroll
    for (int ct = 0; ct < 4; ++ct) {
      floatx4 cacc = (floatx4){0.f, 0.f, 0.f, 0.f};
#pragma unroll
      for (int kk = 0; kk < 4; ++kk) {
        int phys = (kk * 4 + quad) ^ l15;
        half8 bF = *reinterpret_cast<const half8*>(&Kc[(ct * 16 + l15) * 128 + phys * 8]);
        cacc = __builtin_amdgcn_mfma_f32_16x16x32_f16(qF[kk], bF, cacc, 0, 0, 0);
      }
#pragma unroll
      for (int r = 0; r < 4; ++r) {
        float s = cacc[r];
        if (jcur == i && (ct * 16 + l15) > (w * 16 + quad * 4 + r)) s = -1e30f;
        float p = __builtin_exp2f(fmaf(s, SC_L2, -SMAX_L2));
        _Float16 ph = (_Float16)p;           // quantize ONCE; numerator and
        ls[r] += (float)ph;                  // denominator see the same value
        Ps[w * 1024 + (quad * 4 + r) * 64 + ct * 16 + l15] = __builtin_bit_cast(u16, ph);
      }
    }
#pragma unroll
    for (int kk2 = 0; kk2 < 2; ++kk2) {
      half8 aP = *reinterpret_cast<const half8*>(&Ps[w * 1024 + l15 * 64 + kk2 * 32 + quad * 8]);
#pragma unroll
      for (int ct2 = 0; ct2 < 8; ++ct2) {
        int phys = (kk2 * 4 + quad) ^ (l15 & 7);
        half8 bV = *reinterpret_cast<const half8*>(&Vc[(ct2 * 16 + l15) * 64 + phys * 8]);
        o[ct2] = __builtin_amdgcn_mfma_f32_16x16x32_f16(aP, bV, o[ct2], 0, 0, 0);
      }
    }
    BAR();                                        // all waves done reading cur before restage
    if (!hn) break;
    jcur = jn; cur ^= 1;
  }

#pragma unroll
  for (int xm = 1; xm < 16; xm <<= 1)
#pragma unroll
    for (int r = 0; r < 4; ++r) ls[r] += __shfl_xor(ls[r], xm, 64);
  float invl[4];
#pragma unroll
  for (int r = 0; r < 4; ++r) invl[r] = 1.0f / ls[r];
#pragma unroll
  for (int ct2 = 0; ct2 < 8; ++ct2)
#pragma unroll
    for (int r = 0; r < 4; ++r) {
      size_t row = (size_t)(b * S_ + i * 64 + w * 16 + quad * 4 + r);
      attn[row * 2048 + h * 128 + ct2 * 16 + l15] = f2h_bits(o[ct2][r] * invl[r]);
    }
}

extern "C" void kernel_launch(void* const* d_in, const int* in_sizes, int n_in,
                              void* d_out, int out_size, void* d_ws, size_t ws_size,
                              hipStream_t stream) {
  const float* hs = (const float*)d_in[0];
  const float* cosb = (const float*)d_in[1];
  const float* sinb = (const float*)d_in[2];
  const float* Wq = (const float*)d_in[3];
  const float* Wk = (const float*)d_in[4];
  const float* Wv = (const float*)d_in[5];
  const float* Wo = (const float*)d_in[6];
  float* out = (float*)d_out;
  char* ws = (char*)d_ws;

  // phase-1 buffers
  u16* A2 = (u16*)(ws + 0);               // 4096x4096 f16 (hs splits [s0|s1])        [0, 33.5M)
  u16* B2T = (u16*)(ws + 33554432);       // 2560x4096 f16 ([WqT;WkT] splits [t0|t1]) [33.5M, 54.5M)
  u16* WvT = (u16*)(ws + 54525952);       // 512x2048 f16                             [54.5M, 56.6M)
  float* qkv = (float*)(ws + 56623104);   // 4096x3072 f32                            [56.6M, 107M)
  u16* corr = (u16*)out;                  // 4096x2560 f16 correction partial -- d_out is dead
                                          // until k_gemm_wo overwrites it at the very end
  // phase-2 aliases (dead GEMM inputs reused)
  u16* attn = (u16*)(ws + 0);             // 4096x2048 f16  (in dead A2)
  u16* qbf = (u16*)(ws + 16777216);       // (in dead A2)
  u16* kbf = (u16*)(ws + 33554432);       // (in dead B2T)
  u16* vTbf = (u16*)(ws + 37748736);
  float* qblk = (float*)(ws + 41943040);
  float* kblk = (float*)(ws + 42467328);
  int* mask = (int*)(ws + 42598400);
  u16* WoT = (u16*)(ws + 43122688);       // 2048x2048 f16  (in dead B2T; written after QK GEMM)

  (void)in_sizes; (void)n_in; (void)out_size; (void)ws_size;

  // fused prep: split_hs + Wq/Wk/Wv transposes (one launch)
  k_prep<<<9728, 256, 0, stream>>>(hs, A2, Wq, Wk, Wv, B2T, WvT);

  // QKV: balanced 352 blocks (corr NT=64 first; XCD-chunked panel swizzle); no atomics
  k_gemm_qkv<<<352, 512, 0, stream>>>(A2, B2T, WvT, qkv, corr);

  // Wo transpose into dead B2T space (after QK GEMM consumed B2T)
  k_transpose_split<<<dim3(32, 32), 256, 0, stream>>>(Wo, WoT, 2048, 2048, 2048, 1);

  // RoPE (+corr add) + f16 q/k + fp32 block means; V layout
  k_rope_mean<<<dim3(10, 32, 2), 256, 0, stream>>>(qkv, corr, cosb, sinb, qbf, kbf, qblk, kblk);
  k_vlayout<<<dim3(32, 4, 2), 256, 0, stream>>>(qkv, vTbf);

  // gate mask
  k_gate<<<dim3(16, 2), 256, 0, stream>>>(qblk, kblk, mask);

  // block-sparse flash attention (pipelined K/V double-buffer, counted vmcnt)
  k_flash<<<1024, 256, 0, stream>>>(qbf, kbf, vTbf, mask, attn);

  // out = attn @ Wo: 256 blocks of 128x256, full K, no reduction kernel
  k_gemm_wo<<<256, 512, 0, stream>>>(attn, WoT, out);
}

// Round 12
// 369.621 us; speedup vs baseline: 1.1991x; 1.0510x over previous
//
#include <hip/hip_runtime.h>
#include <stdint.h>

typedef unsigned short u16;
typedef _Float16 half8 __attribute__((ext_vector_type(8)));
typedef float floatx4 __attribute__((ext_vector_type(4)));
typedef u16 u16x4 __attribute__((ext_vector_type(4)));

#define B_ 2
#define S_ 2048
#define HID_ 2048
#define H_ 16
#define HKV_ 4
#define D_ 128
#define NB_ 32
#define SCALE_ 0.08838834764831845f
// p = exp(s*SCALE - 4) == exp2(fma(s, SC_L2, -SMAX_L2))
#define SC_L2 0.12753102331884178f
#define SMAX_L2 5.770780163555852f

__device__ __forceinline__ u16 f2h_bits(float f) {
  _Float16 h = (_Float16)f;
  return __builtin_bit_cast(u16, h);
}

// ---- transpose body: W (Kdim x N) tile -> dst rows n: [split0 K | split1 K ...], f16 ----
__device__ __forceinline__ void transpose_body(const float* __restrict__ src, u16* __restrict__ dst,
                                               int Kdim, int N, int ldd, int nsplit,
                                               int k0, int n0, float (*tile)[65]) {
#pragma unroll
  for (int p = 0; p < 16; ++p) {
    int e = threadIdx.x + p * 256;
    int r = e >> 6, c = e & 63;
    tile[r][c] = src[(size_t)(k0 + r) * N + n0 + c];
  }
  __syncthreads();
#pragma unroll
  for (int p = 0; p < 16; ++p) {
    int e = threadIdx.x + p * 256;
    int k = e & 63, n = e >> 6;
    float v = tile[k][n];
    for (int s = 0; s < nsplit; ++s) {
      _Float16 hh = (_Float16)v;
      dst[(size_t)(n0 + n) * ldd + s * Kdim + k0 + k] = __builtin_bit_cast(u16, hh);
      v -= (float)hh;
    }
  }
}

// ---- fused prep: split_hs (8192 blocks) + Wq (1024) + Wk (256) + Wv (256) transposes ----
__global__ __launch_bounds__(256) void k_prep(const float* __restrict__ hs, u16* __restrict__ A2,
                                              const float* __restrict__ Wq, const float* __restrict__ Wk,
                                              const float* __restrict__ Wv,
                                              u16* __restrict__ B2T, u16* __restrict__ WvT) {
  __shared__ float tile[64][65];
  int id = blockIdx.x;
  if (id < 8192) {
    int idx = id * 256 + threadIdx.x;
    int f0 = idx * 4;
    float4 v = *reinterpret_cast<const float4*>(hs + f0);
    float vv[4] = {v.x, v.y, v.z, v.w};
    u16x4 h0, h1;
#pragma unroll
    for (int e = 0; e < 4; ++e) {
      _Float16 a = (_Float16)vv[e];
      float r = vv[e] - (float)a;
      _Float16 b = (_Float16)r;
      h0[e] = __builtin_bit_cast(u16, a);
      h1[e] = __builtin_bit_cast(u16, b);
    }
    int row = f0 >> 11;
    int col = f0 & 2047;
    *reinterpret_cast<u16x4*>(A2 + (size_t)row * 4096 + col) = h0;
    *reinterpret_cast<u16x4*>(A2 + (size_t)row * 4096 + 2048 + col) = h1;
  } else if (id < 9216) {
    int t = id - 8192;
    transpose_body(Wq, B2T, 2048, 2048, 4096, 2, (t & 31) * 64, (t >> 5) * 64, tile);
  } else if (id < 9472) {
    int t = id - 9216;
    transpose_body(Wk, B2T + (size_t)2048 * 4096, 2048, 512, 4096, 2, (t & 31) * 64, (t >> 5) * 64, tile);
  } else {
    int t = id - 9472;
    transpose_body(Wv, WvT, 2048, 512, 2048, 1, (t & 31) * 64, (t >> 5) * 64, tile);
  }
}

// ============ 256x256 GEMM, BK=64, 4-half LDS ring, counted vmcnt (64KB static LDS) ============
// 4-BARRIER variant (round-12): the pre-MM barrier of each phase is redundant — every MM
// drains its own ds_reads (compiler lgkmcnt before MFMA), so the POST-MM barrier already
// guarantees all waves finished reading the half that the next phase restages; cross-wave
// visibility of staged halves = own WAITVM + post-MM BAR. vmcnt ledger IDENTICAL to the
// proven 8-BAR ring (invariant entering ph1: [BH:2, AH:2] = 4):
//   ph1: RD AL,BL ; WAITVM(2) [BH(t) ok]      ; MM(0,0) ; BAR
//   ph2: RD BH ; stage AL',BL' ; WAITVM(4) [AH(t) ok] ; MM(0,1) ; BAR
//   ph3: RD AH ; stage BH'     ;                        MM(1,1) ; BAR
//   ph4: stage AH' ; WAITVM(4) [AL',BL' ok]  ; MM(1,0) ; BAR

#define FENCE() __builtin_amdgcn_sched_barrier(0)
#define BAR() do { FENCE(); __builtin_amdgcn_s_barrier(); FENCE(); } while (0)
#define WAITVM(N) do { FENCE(); asm volatile("s_waitcnt vmcnt(" #N ")" ::: "memory"); FENCE(); } while (0)

__device__ __forceinline__ int kmap(int map, int t) {
  return ((map >> ((t >> 5) * 4)) & 15) * 2048 + (t & 31) * 64;
}

__device__ __forceinline__ void stage_half(const u16* __restrict__ src, int sr0, int lda, int kb,
                                           u16* dst, int w, int lane) {
#pragma unroll
  for (int rr = 0; rr < 2; ++rr) {
    int chunk = rr * 8 + w;                  // 0..15, wave-uniform
    int row = chunk * 8 + (lane >> 3);       // 0..127
    int slot = (lane & 7) ^ (lane >> 3);     // inverse swizzle (row&7 == lane>>3)
    const u16* gp = src + (size_t)(sr0 + row) * lda + kb + slot * 8;
    __builtin_amdgcn_global_load_lds((const __attribute__((address_space(1))) unsigned int*)gp,
                                     (__attribute__((address_space(3))) unsigned int*)(dst + chunk * 512),
                                     16, 0, 0);
  }
}

#define RD_A(mh) do { \
  _Pragma("unroll") \
  for (int m_ = 0; m_ < 4; ++m_) { \
    aF[m_][0] = *reinterpret_cast<const half8*>(&sm[(mh)*8192 + (wm*64 + m_*16 + l15)*64 + ((quad ^ l7) * 8)]); \
    aF[m_][1] = *reinterpret_cast<const half8*>(&sm[(mh)*8192 + (wm*64 + m_*16 + l15)*64 + (((4 + quad) ^ l7) * 8)]); \
  } } while (0)

#define RD_B(nh, BF) do { \
  _Pragma("unroll") \
  for (int n_ = 0; n_ < 2; ++n_) { \
    BF[n_][0] = *reinterpret_cast<const half8*>(&sm[16384 + (nh)*8192 + (wn*32 + n_*16 + l15)*64 + ((quad ^ l7) * 8)]); \
    BF[n_][1] = *reinterpret_cast<const half8*>(&sm[16384 + (nh)*8192 + (wn*32 + n_*16 + l15)*64 + (((4 + quad) ^ l7) * 8)]); \
  } } while (0)

#define MM(mh, nh, BF) do { \
  __builtin_amdgcn_s_setprio(1); \
  _Pragma("unroll") \
  for (int m_ = 0; m_ < 4; ++m_) \
  _Pragma("unroll") \
  for (int n_ = 0; n_ < 2; ++n_) { \
    acc[(mh)*4 + m_][(nh)*2 + n_] = __builtin_amdgcn_mfma_f32_16x16x32_f16(aF[m_][0], BF[n_][0], acc[(mh)*4 + m_][(nh)*2 + n_], 0, 0, 0); \
    acc[(mh)*4 + m_][(nh)*2 + n_] = __builtin_amdgcn_mfma_f32_16x16x32_f16(aF[m_][1], BF[n_][1], acc[(mh)*4 + m_][(nh)*2 + n_], 0, 0, 0); \
  } \
  __builtin_amdgcn_s_setprio(0); } while (0)

__device__ __forceinline__ void gemm256(const u16* __restrict__ A, const u16* __restrict__ BT,
                                        float* __restrict__ C, u16* __restrict__ Ch, u16* sm,
                                        int row0, int col0, int NT,
                                        int lda, int ldb, int ldc, int ldch,
                                        int amap, int bmap) {
  const int tid = (int)threadIdx.x;
  const int lane = tid & 63;
  const int w = tid >> 6;
  const int wm = w >> 2, wn = w & 3;
  const int quad = lane >> 4, l15 = lane & 15, l7 = lane & 7;

  floatx4 acc[8][4];
#pragma unroll
  for (int i = 0; i < 8; ++i)
#pragma unroll
    for (int j = 0; j < 4; ++j) acc[i][j] = (floatx4){0.f, 0.f, 0.f, 0.f};

  half8 aF[4][2], bF0[2][2], bF1[2][2];

  // prologue: stage tile 0 (AL,BL oldest so vmcnt(4) drains them first)
  {
    int ka = kmap(amap, 0), kb = kmap(bmap, 0);
    stage_half(A,  row0,       lda, ka, sm + 0,     w, lane);  // AL
    stage_half(BT, col0,       ldb, kb, sm + 16384, w, lane);  // BL
    stage_half(BT, col0 + 128, ldb, kb, sm + 24576, w, lane);  // BH
    stage_half(A,  row0 + 128, lda, ka, sm + 8192,  w, lane);  // AH
  }
  WAITVM(4);   // own AL,BL landed; BH,AH in flight
  BAR();       // all waves' AL,BL landed before any ds_read

  for (int t = 0; t < NT; ++t) {
    int tn = t + 1; if (tn >= NT) tn = 0;    // clamp keeps vmcnt counts uniform
    int kan = kmap(amap, tn), kbn = kmap(bmap, tn);

    // ph1: quad(0,0) reads AL,BL
    RD_A(0); RD_B(0, bF0);
    WAITVM(2);                                            // BH(t) confirmed (AH in flight)
    MM(0, 0, bF0); BAR();
    // ph2: quad(0,1) reads BH; AL,BL free -> restage for t+1
    RD_B(1, bF1);
    stage_half(A,  row0, lda, kan, sm + 0,     w, lane);  // AL <- t+1
    stage_half(BT, col0, ldb, kbn, sm + 16384, w, lane);  // BL <- t+1
    WAITVM(4);                                            // AH(t) confirmed (AL',BL' in flight)
    MM(0, 1, bF1); BAR();
    // ph3: quad(1,1) reads AH; BH free -> restage
    RD_A(1);
    stage_half(BT, col0 + 128, ldb, kbn, sm + 24576, w, lane);  // BH <- t+1
    MM(1, 1, bF1); BAR();
    // ph4: quad(1,0) register-only (aF from ph3, bF0 from ph1); AH free -> restage
    stage_half(A, row0 + 128, lda, kan, sm + 8192, w, lane);    // AH <- t+1
    WAITVM(4);                                            // AL',BL' confirmed (BH',AH' in flight)
    MM(1, 0, bF0); BAR();
  }
  WAITVM(0);   // drain tail loads before workgroup teardown

  // epilogue: f32 store, or f16 store (correction partial)
#pragma unroll
  for (int i = 0; i < 8; ++i) {
    int mh = i >> 2, m = i & 3;
#pragma unroll
    for (int j = 0; j < 4; ++j) {
      int nh = j >> 1, n = j & 1;
#pragma unroll
      for (int r = 0; r < 4; ++r) {
        int rr = row0 + mh * 128 + wm * 64 + m * 16 + quad * 4 + r;
        int cc = col0 + nh * 128 + wn * 32 + n * 16 + l15;
        if (Ch)
          Ch[(size_t)rr * ldch + cc] = f2h_bits(acc[i][j][r]);
        else
          C[(size_t)rr * ldc + cc] = acc[i][j][r];
      }
    }
  }
}

// ============ 128x256 GEMM variant (BM=128): 48KB LDS ring, 4-BAR, re-derived ledger ============
// Ledger (loads/thread: A=1, B=2). Prologue 6; WAITVM(3) leaves BH(2)+AH(1). Invariant: 3.
//   ph1: RD AL,BL ; WAITVM(1) ; MM ; BAR
//   ph2: RD BH ; stage AL'(1),BL'(2) ; WAITVM(3) ; MM ; BAR
//   ph3: RD AH ; stage BH'(2) ; MM ; BAR
//   ph4: stage AH'(1) ; WAITVM(3) ; MM ; BAR

__device__ __forceinline__ void stage_halfA64(const u16* __restrict__ src, int sr0, int lda, int kb,
                                              u16* dst, int w, int lane) {
  int row = w * 8 + (lane >> 3);             // 0..63
  int slot = (lane & 7) ^ (lane >> 3);       // row&7 == lane>>3
  const u16* gp = src + (size_t)(sr0 + row) * lda + kb + slot * 8;
  __builtin_amdgcn_global_load_lds((const __attribute__((address_space(1))) unsigned int*)gp,
                                   (__attribute__((address_space(3))) unsigned int*)(dst + w * 512),
                                   16, 0, 0);
}

#define RD_A128(mh) do { \
  _Pragma("unroll") \
  for (int m_ = 0; m_ < 2; ++m_) { \
    aF[m_][0] = *reinterpret_cast<const half8*>(&sm[(mh)*4096 + (wm*32 + m_*16 + l15)*64 + ((quad ^ l7) * 8)]); \
    aF[m_][1] = *reinterpret_cast<const half8*>(&sm[(mh)*4096 + (wm*32 + m_*16 + l15)*64 + (((4 + quad) ^ l7) * 8)]); \
  } } while (0)

#define RD_B128(nh, BF) do { \
  _Pragma("unroll") \
  for (int n_ = 0; n_ < 2; ++n_) { \
    BF[n_][0] = *reinterpret_cast<const half8*>(&sm[8192 + (nh)*8192 + (wn*32 + n_*16 + l15)*64 + ((quad ^ l7) * 8)]); \
    BF[n_][1] = *reinterpret_cast<const half8*>(&sm[8192 + (nh)*8192 + (wn*32 + n_*16 + l15)*64 + (((4 + quad) ^ l7) * 8)]); \
  } } while (0)

#define MM128(mh, nh, BF) do { \
  __builtin_amdgcn_s_setprio(1); \
  _Pragma("unroll") \
  for (int m_ = 0; m_ < 2; ++m_) \
  _Pragma("unroll") \
  for (int n_ = 0; n_ < 2; ++n_) { \
    acc[(mh)*2 + m_][(nh)*2 + n_] = __builtin_amdgcn_mfma_f32_16x16x32_f16(aF[m_][0], BF[n_][0], acc[(mh)*2 + m_][(nh)*2 + n_], 0, 0, 0); \
    acc[(mh)*2 + m_][(nh)*2 + n_] = __builtin_amdgcn_mfma_f32_16x16x32_f16(aF[m_][1], BF[n_][1], acc[(mh)*2 + m_][(nh)*2 + n_], 0, 0, 0); \
  } \
  __builtin_amdgcn_s_setprio(0); } while (0)

__device__ __forceinline__ void gemm128(const u16* __restrict__ A, const u16* __restrict__ BT,
                                        float* __restrict__ C, u16* sm,
                                        int row0, int col0, int NT,
                                        int lda, int ldb, int ldc) {
  const int tid = (int)threadIdx.x;
  const int lane = tid & 63;
  const int w = tid >> 6;
  const int wm = w >> 2, wn = w & 3;
  const int quad = lane >> 4, l15 = lane & 15, l7 = lane & 7;

  floatx4 acc[4][4];
#pragma unroll
  for (int i = 0; i < 4; ++i)
#pragma unroll
    for (int j = 0; j < 4; ++j) acc[i][j] = (floatx4){0.f, 0.f, 0.f, 0.f};

  half8 aF[2][2], bF0[2][2], bF1[2][2];

  // prologue
  stage_halfA64(A,  row0,      lda, 0, sm + 0,     w, lane);  // AL (1)
  stage_half  (BT, col0,       ldb, 0, sm + 8192,  w, lane);  // BL (2)
  stage_half  (BT, col0 + 128, ldb, 0, sm + 16384, w, lane);  // BH (2)
  stage_halfA64(A,  row0 + 64, lda, 0, sm + 4096,  w, lane);  // AH (1)
  WAITVM(3);
  BAR();

  for (int t = 0; t < NT; ++t) {
    int tn = t + 1; if (tn >= NT) tn = 0;
    int kn = tn * 64;

    // ph1: quad(0,0) reads AL,BL
    RD_A128(0); RD_B128(0, bF0);
    WAITVM(1);                                              // BH confirmed (AH in flight)
    MM128(0, 0, bF0); BAR();
    // ph2: quad(0,1) reads BH; restage AL,BL
    RD_B128(1, bF1);
    stage_halfA64(A,  row0, lda, kn, sm + 0,    w, lane);   // AL' (1)
    stage_half  (BT, col0, ldb, kn, sm + 8192,  w, lane);   // BL' (2)
    WAITVM(3);                                              // AH confirmed
    MM128(0, 1, bF1); BAR();
    // ph3: quad(1,1) reads AH; restage BH
    RD_A128(1);
    stage_half(BT, col0 + 128, ldb, kn, sm + 16384, w, lane); // BH' (2)
    MM128(1, 1, bF1); BAR();
    // ph4: quad(1,0) register-only; restage AH
    stage_halfA64(A, row0 + 64, lda, kn, sm + 4096, w, lane); // AH' (1)
    WAITVM(3);                                              // AL',BL' confirmed
    MM128(1, 0, bF0); BAR();
  }
  WAITVM(0);

#pragma unroll
  for (int i = 0; i < 4; ++i) {
    int mh = i >> 1, m = i & 1;
#pragma unroll
    for (int j = 0; j < 4; ++j) {
      int nh = j >> 1, n = j & 1;
#pragma unroll
      for (int r = 0; r < 4; ++r) {
        int rr = row0 + mh * 64 + wm * 32 + m * 16 + quad * 4 + r;
        int cc = col0 + nh * 128 + wn * 32 + n * 16 + l15;
        C[(size_t)rr * ldc + cc] = acc[i][j][r];
      }
    }
  }
}

// ---- fused QKV projection, balanced 352-block grid, no atomics ----
// Physical ids 0..159 = correction (NT=64, dispatched first -> 1/CU at t=0);
// 160..319 = main QK (NT=32); 320..351 = V (NT=32).
// XCD-chunked swizzle within each 160-band: logical = (p%8)*20 + p/8 (bijective).
__global__ __launch_bounds__(512) void k_gemm_qkv(const u16* __restrict__ A2, const u16* __restrict__ B2T,
                                                  const u16* __restrict__ WvT, float* __restrict__ qkv,
                                                  u16* __restrict__ corr) {
  __shared__ u16 sm[32768];   // 64KB
  int id = blockIdx.x;
  if (id < 160) {
    int lg = (id & 7) * 20 + (id >> 3);          // XCD-chunk: 2 row-panels per XCD
    int row0 = (lg / 10) * 256, col0 = (lg % 10) * 256;
    gemm256(A2, B2T, nullptr, corr, sm, row0, col0, 64, 4096, 4096, 0, 2560, 0x01, 0x10);
  } else if (id < 320) {
    int t = id - 160;
    int lg = (t & 7) * 20 + (t >> 3);
    int row0 = (lg / 10) * 256, col0 = (lg % 10) * 256;
    gemm256(A2, B2T, qkv, nullptr, sm, row0, col0, 32, 4096, 4096, 3072, 0, 0, 0);
  } else {
    int t = id - 320;
    int row0 = (t >> 1) * 256, col0 = (t & 1) * 256;
    gemm256(A2, WvT, qkv + 2560, nullptr, sm, row0, col0, 32, 4096, 2048, 3072, 0, 0, 0);
  }
}

// ---- out = attn @ Wo: 256 blocks of 128x256, full K, full-chip balance, no reduction ----
__global__ __launch_bounds__(512) void k_gemm_wo(const u16* __restrict__ attn, const u16* __restrict__ WoT,
                                                 float* __restrict__ out) {
  __shared__ u16 sm[24576];   // 48KB
  int id = blockIdx.x;
  gemm128(attn, WoT, out, sm, (id >> 3) * 128, (id & 7) * 256, 32, 2048, 2048, 2048);
}

// ---- fused mid stage: RoPE(+corr) [640] + Wo transpose [1024] + V layout [256] ----
// All three depend only on the QKV GEMM; banded into one 1920-block launch (rope first:
// heaviest per block -> better makespan/tail packing). Saves 2 launch gaps.
__global__ __launch_bounds__(256) void k_mid(const float* __restrict__ qkv, const u16* __restrict__ corr,
                                             const float* __restrict__ cosb, const float* __restrict__ sinb,
                                             u16* __restrict__ qbf, u16* __restrict__ kbf,
                                             float* __restrict__ qblk, float* __restrict__ kblk,
                                             const float* __restrict__ Wo, u16* __restrict__ WoT,
                                             u16* __restrict__ vT) {
  __shared__ __align__(16) char smem[16640];   // union: float[64][65] (transpose) / u16[64*130] (vlayout)
  int id = blockIdx.x;
  if (id < 640) {
    // ---- RoPE (+f16 correction add) + q/k f16 + fp32 block means ----
    int t = id;
    int cc = t % 10, i = (t / 10) & 31, b = t / 320;
    int c = cc * 256 + (int)threadIdx.x;       // 0..2559
    bool isq = c < 2048;
    int hh = isq ? (c >> 7) : ((c - 2048) >> 7);
    int d = isq ? (c & 127) : ((c - 2048) & 127);
    int pairc = (d < 64) ? c + 64 : c - 64;
    float sgn = (d < 64) ? -1.0f : 1.0f;
    int row0 = b * S_ + i * 64;
    float sum = 0.0f;
    for (int s = 0; s < 64; ++s) {
      int row = row0 + s;
      float x1 = qkv[(size_t)row * 3072 + c]
               + (float)__builtin_bit_cast(_Float16, corr[(size_t)row * 2560 + c]);
      float x2 = qkv[(size_t)row * 3072 + pairc]
               + (float)__builtin_bit_cast(_Float16, corr[(size_t)row * 2560 + pairc]);
      float cv = cosb[(size_t)row * 128 + d];
      float sv = sinb[(size_t)row * 128 + d];
      float val = x1 * cv + sgn * x2 * sv;
      sum += val;
      if (isq)
        qbf[((size_t)(b * H_ + hh) * S_ + i * 64 + s) * 128 + d] = f2h_bits(val);
      else
        kbf[((size_t)(b * HKV_ + hh) * S_ + i * 64 + s) * 128 + d] = f2h_bits(val);
    }
    if (isq)
      qblk[((size_t)(b * H_ + hh) * NB_ + i) * 128 + d] = sum * 0.015625f;
    else
      kblk[((size_t)(b * HKV_ + hh) * NB_ + i) * 128 + d] = sum * 0.015625f;
  } else if (id < 1664) {
    // ---- Wo transpose (into dead B2T space) ----
    int t = id - 640;
    transpose_body(Wo, WoT, 2048, 2048, 2048, 1, (t & 31) * 64, (t >> 5) * 64,
                   reinterpret_cast<float(*)[65]>(smem));
  } else {
    // ---- V -> f16 transposed layout (B,HKV,D,S) ----
    int t = id - 1664;
    int i = t & 31, hk = (t >> 5) & 3, b = t >> 7;
    u16* tile = (u16*)smem;
#pragma unroll
    for (int p = 0; p < 32; ++p) {
      int e = threadIdx.x + p * 256;
      int s = e >> 7, d = e & 127;
      float v = qkv[(size_t)(b * S_ + i * 64 + s) * 3072 + 2560 + hk * 128 + d];
      tile[s * 130 + d] = f2h_bits(v);
    }
    __syncthreads();
#pragma unroll
    for (int p = 0; p < 32; ++p) {
      int e = threadIdx.x + p * 256;
      int d2 = e >> 6, s2 = e & 63;
      vT[((size_t)(b * HKV_ + hk) * 128 + d2) * S_ + i * 64 + s2] = tile[s2 * 130 + d2];
    }
  }
}

// ---- gate mask: sigmoid(logit)>=0.5 <=> dot>=0; | eye; & tril ----
__global__ __launch_bounds__(256) void k_gate(const float* __restrict__ qblk, const float* __restrict__ kblk,
                                              int* __restrict__ mask) {
  int h = blockIdx.x, b = blockIdx.y;
  int hk = h >> 2;
  __shared__ float qs[32 * 128];
  __shared__ float ks[32 * 128];
  size_t qb0 = (size_t)(b * H_ + h) * NB_ * 128;
  size_t kb0 = (size_t)(b * HKV_ + hk) * NB_ * 128;
#pragma unroll
  for (int p = 0; p < 16; ++p) {
    int e = threadIdx.x + p * 256;
    qs[e] = qblk[qb0 + e];
    ks[e] = kblk[kb0 + e];
  }
  __syncthreads();
#pragma unroll
  for (int p = 0; p < 4; ++p) {
    int l = threadIdx.x + p * 256;
    int i = l >> 5, j = l & 31;
    int m;
    if (j > i) m = 0;
    else if (j == i) m = 1;
    else {
      float dot = 0.0f;
      for (int d = 0; d < 128; ++d) dot += qs[i * 128 + d] * ks[j * 128 + d];
      m = (dot >= 0.0f) ? 1 : 0;
    }
    mask[((size_t)(b * H_ + h) * NB_ + i) * NB_ + j] = m;
  }
}

// ---- block-sparse flash attention, static-max softmax, PIPELINED K/V staging ----
// Double-buffered Ks/Vs (72KB LDS); counted WAITVM(8) drains only the CURRENT tile's 8
// loads while the next tile's 8 fly under compute. Heavy blocks (large i) dispatched first.
__global__ __launch_bounds__(256) void k_flash(const u16* __restrict__ qbf, const u16* __restrict__ kbf,
                                               const u16* __restrict__ vT, const int* __restrict__ mask,
                                               u16* __restrict__ attn) {
  const int id = blockIdx.x;
  const int i = 31 - (id >> 5);     // reverse: heavy rows first for makespan
  const int hb = id & 31;
  const int h = hb & 15, b = hb >> 4;
  const int hk = h >> 2;
  const int tid = threadIdx.x;
  const int lane = tid & 63;
  const int w = tid >> 6;
  const int quad = lane >> 4;
  const int l15 = lane & 15;

  __shared__ u16 Ksb[2 * 64 * 128];  // [buf][tok][d], swizzle u_phys = u ^ (tok&15)
  __shared__ u16 Vsb[2 * 128 * 64];  // [buf][d][tok], swizzle u_phys = u ^ (dd&7)
  __shared__ u16 Ps[4 * 16 * 64];    // per-wave [m][k]

  half8 qF[4];
  const u16* qbase = qbf + ((size_t)(b * H_ + h) * S_ + i * 64 + w * 16 + l15) * 128;
#pragma unroll
  for (int kk = 0; kk < 4; ++kk)
    qF[kk] = *reinterpret_cast<const half8*>(qbase + kk * 32 + quad * 8);

  floatx4 o[8];
#pragma unroll
  for (int t = 0; t < 8; ++t) o[t] = (floatx4){0.f, 0.f, 0.f, 0.f};
  float ls[4] = {0.f, 0.f, 0.f, 0.f};

  const u16* kb = kbf + (size_t)(b * HKV_ + hk) * S_ * 128;
  const u16* vb = vT + (size_t)(b * HKV_ + hk) * 128 * S_;
  const int* mrp = mask + ((size_t)(b * H_ + h) * NB_ + i) * NB_;

#define FSTAGE(J, BUF) do { \
  _Pragma("unroll") \
  for (int t_ = 0; t_ < 4; ++t_) { \
    int g2 = t_ * 4 + w; \
    int stok = g2 * 4 + (lane >> 4); \
    int ul = (lane & 15) ^ (stok & 15); \
    const u16* srcK = kb + (size_t)((J) * 64 + stok) * 128 + ul * 8; \
    __builtin_amdgcn_global_load_lds((const __attribute__((address_space(1))) unsigned int*)srcK, \
                                     (__attribute__((address_space(3))) unsigned int*)(Ksb + (BUF) * 8192 + g2 * 512), \
                                     16, 0, 0); \
    int sdd = g2 * 8 + (lane >> 3); \
    int ulv = (lane & 7) ^ (sdd & 7); \
    const u16* srcV = vb + (size_t)sdd * S_ + (J) * 64 + ulv * 8; \
    __builtin_amdgcn_global_load_lds((const __attribute__((address_space(1))) unsigned int*)srcV, \
                                     (__attribute__((address_space(3))) unsigned int*)(Vsb + (BUF) * 8192 + g2 * 512), \
                                     16, 0, 0); \
  } } while (0)

  int jcur = 0;
  while (!mrp[jcur]) ++jcur;        // diag guarantees jcur <= i
  FSTAGE(jcur, 0);                  // prologue: 8 loads in flight
  int cur = 0;

  for (;;) {
    int jn = jcur + 1;
    while (jn <= i && !mrp[jn]) ++jn;
    bool hn = (jn <= i);
    if (hn) { FSTAGE(jn, cur ^ 1); WAITVM(8); }   // jcur's 8 done; jn's 8 in flight
    else    { WAITVM(0); }
    BAR();                                        // all waves' jcur loads landed

    const u16* Kc = Ksb + cur * 8192;
    const u16* Vc = Vsb + cur * 8192;
#pragma unroll
    for (int ct = 0; ct < 4; ++ct) {
      floatx4 cacc = (floatx4){0.f, 0.f, 0.f, 0.f};
#pragma unroll
      for (int kk = 0; kk < 4; ++kk) {
        int phys = (kk * 4 + quad) ^ l15;
        half8 bF = *reinterpret_cast<const half8*>(&Kc[(ct * 16 + l15) * 128 + phys * 8]);
        cacc = __builtin_amdgcn_mfma_f32_16x16x32_f16(qF[kk], bF, cacc, 0, 0, 0);
      }
#pragma unroll
      for (int r = 0; r < 4; ++r) {
        float s = cacc[r];
        if (jcur == i && (ct * 16 + l15) > (w * 16 + quad * 4 + r)) s = -1e30f;
        float p = __builtin_exp2f(fmaf(s, SC_L2, -SMAX_L2));
        _Float16 ph = (_Float16)p;           // quantize ONCE; numerator and
        ls[r] += (float)ph;                  // denominator see the same value
        Ps[w * 1024 + (quad * 4 + r) * 64 + ct * 16 + l15] = __builtin_bit_cast(u16, ph);
      }
    }
#pragma unroll
    for (int kk2 = 0; kk2 < 2; ++kk2) {
      half8 aP = *reinterpret_cast<const half8*>(&Ps[w * 1024 + l15 * 64 + kk2 * 32 + quad * 8]);
#pragma unroll
      for (int ct2 = 0; ct2 < 8; ++ct2) {
        int phys = (kk2 * 4 + quad) ^ (l15 & 7);
        half8 bV = *reinterpret_cast<const half8*>(&Vc[(ct2 * 16 + l15) * 64 + phys * 8]);
        o[ct2] = __builtin_amdgcn_mfma_f32_16x16x32_f16(aP, bV, o[ct2], 0, 0, 0);
      }
    }
    BAR();                                        // all waves done reading cur before restage
    if (!hn) break;
    jcur = jn; cur ^= 1;
  }

#pragma unroll
  for (int xm = 1; xm < 16; xm <<= 1)
#pragma unroll
    for (int r = 0; r < 4; ++r) ls[r] += __shfl_xor(ls[r], xm, 64);
  float invl[4];
#pragma unroll
  for (int r = 0; r < 4; ++r) invl[r] = 1.0f / ls[r];
#pragma unroll
  for (int ct2 = 0; ct2 < 8; ++ct2)
#pragma unroll
    for (int r = 0; r < 4; ++r) {
      size_t row = (size_t)(b * S_ + i * 64 + w * 16 + quad * 4 + r);
      attn[row * 2048 + h * 128 + ct2 * 16 + l15] = f2h_bits(o[ct2][r] * invl[r]);
    }
}

extern "C" void kernel_launch(void* const* d_in, const int* in_sizes, int n_in,
                              void* d_out, int out_size, void* d_ws, size_t ws_size,
                              hipStream_t stream) {
  const float* hs = (const float*)d_in[0];
  const float* cosb = (const float*)d_in[1];
  const float* sinb = (const float*)d_in[2];
  const float* Wq = (const float*)d_in[3];
  const float* Wk = (const float*)d_in[4];
  const float* Wv = (const float*)d_in[5];
  const float* Wo = (const float*)d_in[6];
  float* out = (float*)d_out;
  char* ws = (char*)d_ws;

  // phase-1 buffers
  u16* A2 = (u16*)(ws + 0);               // 4096x4096 f16 (hs splits [s0|s1])        [0, 33.5M)
  u16* B2T = (u16*)(ws + 33554432);       // 2560x4096 f16 ([WqT;WkT] splits [t0|t1]) [33.5M, 54.5M)
  u16* WvT = (u16*)(ws + 54525952);       // 512x2048 f16                             [54.5M, 56.6M)
  float* qkv = (float*)(ws + 56623104);   // 4096x3072 f32                            [56.6M, 107M)
  u16* corr = (u16*)out;                  // 4096x2560 f16 correction partial -- d_out is dead
                                          // until k_gemm_wo overwrites it at the very end
  // phase-2 aliases (dead GEMM inputs reused)
  u16* attn = (u16*)(ws + 0);             // 4096x2048 f16  (in dead A2)
  u16* qbf = (u16*)(ws + 16777216);       // (in dead A2)
  u16* kbf = (u16*)(ws + 33554432);       // (in dead B2T)
  u16* vTbf = (u16*)(ws + 37748736);
  float* qblk = (float*)(ws + 41943040);
  float* kblk = (float*)(ws + 42467328);
  int* mask = (int*)(ws + 42598400);
  u16* WoT = (u16*)(ws + 43122688);       // 2048x2048 f16  (in dead B2T; written after QK GEMM)

  (void)in_sizes; (void)n_in; (void)out_size; (void)ws_size;

  // fused prep: split_hs + Wq/Wk/Wv transposes (one launch)
  k_prep<<<9728, 256, 0, stream>>>(hs, A2, Wq, Wk, Wv, B2T, WvT);

  // QKV: balanced 352 blocks (corr NT=64 first; XCD-chunked panel swizzle); no atomics
  k_gemm_qkv<<<352, 512, 0, stream>>>(A2, B2T, WvT, qkv, corr);

  // fused mid: RoPE(+corr) + Wo transpose + V layout (one launch)
  k_mid<<<1920, 256, 0, stream>>>(qkv, corr, cosb, sinb, qbf, kbf, qblk, kblk, Wo, WoT, vTbf);

  // gate mask
  k_gate<<<dim3(16, 2), 256, 0, stream>>>(qblk, kblk, mask);

  // block-sparse flash attention (pipelined K/V double-buffer, counted vmcnt)
  k_flash<<<1024, 256, 0, stream>>>(qbf, kbf, vTbf, mask, attn);

  // out = attn @ Wo: 256 blocks of 128x256, full K, no reduction kernel
  k_gemm_wo<<<256, 512, 0, stream>>>(attn, WoT, out);
}